// Round 2
// baseline (11512.255 us; speedup 1.0000x reference)
//
#include <hip/hip_runtime.h>

#define VSZ   32000
#define DSZ   768
#define HN    12
#define HIDSZ 3072
#define NL    2
#define CN    2
#define RR    8
#define SCALEF 2.0f
#define BBATCH 64
#define SSEQ  512
#define HDIM  64
#define NTOK  (BBATCH*SSEQ)   // 32768
#define QKVM  (3*DSZ)         // 2304 — stacked QKV output width

// ---------------------------------------------------------------------------
// Embedding: x[s*B+b, d] = emb_W[tok,d] + SCALE * sum_r emb_A[r,tok]*emb_B[d,r]
// ---------------------------------------------------------------------------
__global__ __launch_bounds__(256) void embed_kernel(
    const int* __restrict__ tokens, const float* __restrict__ embW,
    const float* __restrict__ embA, const float* __restrict__ embB,
    float* __restrict__ x)
{
    int n = blockIdx.x;            // n = s*B + b
    int s = n / BBATCH, b = n % BBATCH;
    int tok = tokens[b * SSEQ + s];
    __shared__ float a[RR];
    if (threadIdx.x < RR) a[threadIdx.x] = embA[(size_t)threadIdx.x * VSZ + tok];
    __syncthreads();
    for (int d = threadIdx.x; d < DSZ; d += 256) {
        float val = embW[(size_t)tok * DSZ + d];
        float lo = 0.f;
        #pragma unroll
        for (int r = 0; r < RR; ++r) lo += a[r] * embB[d * RR + r];
        x[(size_t)n * DSZ + d] = val + SCALEF * lo;
    }
}

// ---------------------------------------------------------------------------
// Effective weight: W'[o,i] = W[o,i] + SCALE * sum_r B[o,r]*A[r,i]
// grid = (K/256, M), block = 256
// ---------------------------------------------------------------------------
__global__ __launch_bounds__(256) void weff_kernel(
    const float* __restrict__ W, const float* __restrict__ A,
    const float* __restrict__ Bm, float* __restrict__ Weff, int K)
{
    int i = blockIdx.x * 256 + threadIdx.x;
    int o = blockIdx.y;
    float acc = W[(size_t)o * K + i];
    #pragma unroll
    for (int r = 0; r < RR; ++r)
        acc += SCALEF * Bm[o * RR + r] * A[(size_t)r * K + i];
    Weff[(size_t)o * K + i] = acc;
}

// Stack three bias vectors of length DSZ into one buffer of length 3*DSZ
__global__ __launch_bounds__(256) void biascat_kernel(
    const float* __restrict__ b0, const float* __restrict__ b1v,
    const float* __restrict__ b2v, float* __restrict__ out)
{
    int t = blockIdx.y * 256 + threadIdx.x;   // 0..767
    const float* src = (blockIdx.x == 0) ? b0 : (blockIdx.x == 1) ? b1v : b2v;
    out[blockIdx.x * DSZ + t] = src[t];
}

// ---------------------------------------------------------------------------
// Tiled FP32 GEMM: Y[n,m] = sum_k X[n,k]*W[m,k] + bias[m]
// X row stride = ldx, Y row stride = ldy, W row stride = K (contiguous).
// 128x128 tile, BK=32, 256 threads, 8x8 micro-tile (quadrant layout).
// ---------------------------------------------------------------------------
#define BT  128
#define BKK 32
#define LDP 132   // 132 floats = 528 B (16B-aligned rows), breaks bank conflicts

template<bool RELU, bool ADDTO>
__global__ __launch_bounds__(256) void gemm_kernel(
    const float* __restrict__ X, const float* __restrict__ W,
    const float* __restrict__ bias, float* __restrict__ Y,
    int K, int M, int ldx, int ldy)
{
    __shared__ __align__(16) float Xs[BKK][LDP];
    __shared__ __align__(16) float Ws[BKK][LDP];
    const int t  = threadIdx.x;
    const int n0 = blockIdx.x * BT;
    const int m0 = blockIdx.y * BT;
    const int tn = t & 15;
    const int tm = t >> 4;
    const int ldk = (t & 7) * 4;   // k offset of this thread's float4
    const int ldr = t >> 3;        // row 0..31 per pass

    float acc[8][8];
    #pragma unroll
    for (int i = 0; i < 8; ++i)
        #pragma unroll
        for (int j = 0; j < 8; ++j) acc[i][j] = 0.f;

    const float* Xp = X + (size_t)(n0 + ldr) * ldx + ldk;
    const float* Wp = W + (size_t)(m0 + ldr) * K + ldk;

    for (int k0 = 0; k0 < K; k0 += BKK) {
        __syncthreads();
        #pragma unroll
        for (int p = 0; p < 4; ++p) {
            float4 xv = *(const float4*)(Xp + (size_t)(p * 32) * ldx + k0);
            float4 wv = *(const float4*)(Wp + (size_t)(p * 32) * K + k0);
            int row = ldr + p * 32;
            Xs[ldk + 0][row] = xv.x; Xs[ldk + 1][row] = xv.y;
            Xs[ldk + 2][row] = xv.z; Xs[ldk + 3][row] = xv.w;
            Ws[ldk + 0][row] = wv.x; Ws[ldk + 1][row] = wv.y;
            Ws[ldk + 2][row] = wv.z; Ws[ldk + 3][row] = wv.w;
        }
        __syncthreads();
        #pragma unroll
        for (int k = 0; k < BKK; ++k) {
            float4 a0 = *(const float4*)&Xs[k][tn * 4];
            float4 a1 = *(const float4*)&Xs[k][64 + tn * 4];
            float4 b0 = *(const float4*)&Ws[k][tm * 4];
            float4 b1 = *(const float4*)&Ws[k][64 + tm * 4];
            float av[8] = {a0.x, a0.y, a0.z, a0.w, a1.x, a1.y, a1.z, a1.w};
            float bv[8] = {b0.x, b0.y, b0.z, b0.w, b1.x, b1.y, b1.z, b1.w};
            #pragma unroll
            for (int i = 0; i < 8; ++i)
                #pragma unroll
                for (int j = 0; j < 8; ++j)
                    acc[i][j] += av[i] * bv[j];
        }
    }

    #pragma unroll
    for (int i = 0; i < 8; ++i) {
        int n = n0 + ((i < 4) ? (tn * 4 + i) : (64 + tn * 4 + i - 4));
        float* yp = Y + (size_t)n * ldy + m0;
        #pragma unroll
        for (int mq = 0; mq < 2; ++mq) {
            int mb = mq * 64 + tm * 4;
            float4 bv4 = *(const float4*)(bias + m0 + mb);
            float4 r;
            r.x = acc[i][mq * 4 + 0] + bv4.x;
            r.y = acc[i][mq * 4 + 1] + bv4.y;
            r.z = acc[i][mq * 4 + 2] + bv4.z;
            r.w = acc[i][mq * 4 + 3] + bv4.w;
            if (RELU) {
                r.x = fmaxf(r.x, 0.f); r.y = fmaxf(r.y, 0.f);
                r.z = fmaxf(r.z, 0.f); r.w = fmaxf(r.w, 0.f);
            }
            if (ADDTO) {
                float4 o = *(const float4*)(yp + mb);
                r.x += o.x; r.y += o.y; r.z += o.z; r.w += o.w;
            }
            *(float4*)(yp + mb) = r;
        }
    }
}

// ---------------------------------------------------------------------------
// Attention over the BATCH axis on the stacked QKV chunk buffer.
// qkv rows (chunk-local n = s'*64 + b) have stride QKVM: [Q(768) K(768) V(768)].
// Per (s',h): 64x64 scores over batch, softmax, PV. Output overwrites Q slot.
// grid = schunk*HN, block = 256.
// ---------------------------------------------------------------------------
__global__ __launch_bounds__(256) void attn_kernel(float* __restrict__ qkv)
{
    __shared__ float Qs[64][65];   // reused for P after scores
    __shared__ float Ks[64][65];
    __shared__ float Vs[64][65];
    const int t = threadIdx.x;
    const int sp = blockIdx.x / HN;
    const int h  = blockIdx.x % HN;
    const size_t base = (size_t)sp * BBATCH * QKVM + h * HDIM;

    #pragma unroll
    for (int i = 0; i < 16; ++i) {
        int e = i * 256 + t;
        int r = e >> 6, c = e & 63;
        size_t rowoff = base + (size_t)r * QKVM + c;
        Qs[r][c] = qkv[rowoff];
        Ks[r][c] = qkv[rowoff + DSZ];
        Vs[r][c] = qkv[rowoff + 2 * DSZ];
    }
    __syncthreads();

    const int br = t >> 2;
    const int c0 = (t & 3) * 16;
    float sc[16];
    #pragma unroll
    for (int cc = 0; cc < 16; ++cc) sc[cc] = 0.f;
    for (int d = 0; d < 64; ++d) {
        float qv = Qs[br][d];
        #pragma unroll
        for (int cc = 0; cc < 16; ++cc) sc[cc] += qv * Ks[c0 + cc][d];
    }
    __syncthreads();   // all reads of Qs done; reuse as P
    #pragma unroll
    for (int cc = 0; cc < 16; ++cc) Qs[br][c0 + cc] = sc[cc] * 0.125f;
    __syncthreads();

    if (t < 64) {
        float mx = -1e30f;
        for (int c = 0; c < 64; ++c) mx = fmaxf(mx, Qs[t][c]);
        float sum = 0.f;
        for (int c = 0; c < 64; ++c) { float e = __expf(Qs[t][c] - mx); Qs[t][c] = e; sum += e; }
        float inv = 1.f / sum;
        for (int c = 0; c < 64; ++c) Qs[t][c] *= inv;
    }
    __syncthreads();

    const int d0 = (t & 3) * 16;
    float ov[16];
    #pragma unroll
    for (int dd = 0; dd < 16; ++dd) ov[dd] = 0.f;
    for (int c = 0; c < 64; ++c) {
        float pv = Qs[br][c];
        #pragma unroll
        for (int dd = 0; dd < 16; ++dd) ov[dd] += pv * Vs[c][d0 + dd];
    }
    #pragma unroll
    for (int dd = 0; dd < 16; ++dd)
        qkv[base + (size_t)br * QKVM + d0 + dd] = ov[dd];   // ao over Q slot
}

// ---------------------------------------------------------------------------
// In-place LayerNorm per row of x (D=768, 256 threads -> 3 elems/thread)
// ---------------------------------------------------------------------------
__device__ __forceinline__ float block_sum256(float vsum, volatile float* red) {
    #pragma unroll
    for (int off = 32; off > 0; off >>= 1) vsum += __shfl_down(vsum, off, 64);
    if ((threadIdx.x & 63) == 0) red[threadIdx.x >> 6] = vsum;
    __syncthreads();
    return red[0] + red[1] + red[2] + red[3];
}

__global__ __launch_bounds__(256) void ln_kernel(
    float* __restrict__ x, const float* __restrict__ g, const float* __restrict__ be)
{
    __shared__ float red1[4];
    __shared__ float red2[4];
    const int n = blockIdx.x;
    const int t = threadIdx.x;
    float* row = x + (size_t)n * DSZ;
    float v0 = row[t], v1 = row[t + 256], v2 = row[t + 512];
    float total = block_sum256(v0 + v1 + v2, red1);
    float mean = total * (1.0f / DSZ);
    float d0 = v0 - mean, d1 = v1 - mean, d2 = v2 - mean;
    __syncthreads();
    float var = block_sum256(d0 * d0 + d1 * d1 + d2 * d2, red2) * (1.0f / DSZ);
    float rstd = rsqrtf(var + 1e-5f);
    row[t]       = d0 * rstd * g[t]       + be[t];
    row[t + 256] = d1 * rstd * g[t + 256] + be[t + 256];
    row[t + 512] = d2 * rstd * g[t + 512] + be[t + 512];
}

// ---------------------------------------------------------------------------
// Mean over S:  xm[b,d] = 1/S * sum_s x[s*B+b, d]
// ---------------------------------------------------------------------------
__global__ __launch_bounds__(256) void meanS_kernel(
    const float* __restrict__ x, float* __restrict__ xm)
{
    int idx = blockIdx.x * 256 + threadIdx.x;   // over B*D, d fastest
    int b = idx / DSZ, d = idx % DSZ;
    float acc = 0.f;
    for (int s = 0; s < SSEQ; ++s)
        acc += x[((size_t)s * BBATCH + b) * DSZ + d];
    xm[idx] = acc * (1.0f / SSEQ);
}

// ---------------------------------------------------------------------------
// Classifier: out[b,c] = xm[b,:]@fcW[c,:] + fcb[c] + SCALE*(xm@fcA^T)@fcB^T
// ---------------------------------------------------------------------------
__global__ __launch_bounds__(128) void fc_kernel(
    const float* __restrict__ xm, const float* __restrict__ fcW,
    const float* __restrict__ fcb, const float* __restrict__ fcA,
    const float* __restrict__ fcBm, float* __restrict__ out)
{
    int t = threadIdx.x;
    if (t >= BBATCH * CN) return;
    int b = t / CN, c = t % CN;
    float acc = fcb[c];
    float lora[RR];
    #pragma unroll
    for (int r = 0; r < RR; ++r) lora[r] = 0.f;
    for (int d = 0; d < DSZ; ++d) {
        float xv = xm[b * DSZ + d];
        acc += xv * fcW[c * DSZ + d];
        #pragma unroll
        for (int r = 0; r < RR; ++r) lora[r] += xv * fcA[r * DSZ + d];
    }
    float lo = 0.f;
    #pragma unroll
    for (int r = 0; r < RR; ++r) lo += lora[r] * fcBm[c * RR + r];
    out[b * CN + c] = acc + SCALEF * lo;
}

// ---------------------------------------------------------------------------
extern "C" void kernel_launch(void* const* d_in, const int* in_sizes, int n_in,
                              void* d_out, int out_size, void* d_ws, size_t ws_size,
                              hipStream_t stream) {
    const int*   tokens = (const int*)  d_in[0];
    const float* embW   = (const float*)d_in[1];
    const float* embA   = (const float*)d_in[2];
    const float* embB   = (const float*)d_in[3];
    const float* Wq = (const float*)d_in[4],  *bq = (const float*)d_in[5],
               * Aq = (const float*)d_in[6],  *Bq = (const float*)d_in[7];
    const float* Wk = (const float*)d_in[8],  *bk = (const float*)d_in[9],
               * Ak = (const float*)d_in[10], *Bk = (const float*)d_in[11];
    const float* Wv = (const float*)d_in[12], *bv = (const float*)d_in[13],
               * Av = (const float*)d_in[14], *Bv = (const float*)d_in[15];
    const float* Wo = (const float*)d_in[16], *bo = (const float*)d_in[17],
               * Ao = (const float*)d_in[18], *Bo = (const float*)d_in[19];
    const float* W1 = (const float*)d_in[20], *b1 = (const float*)d_in[21],
               * A1 = (const float*)d_in[22], *B1 = (const float*)d_in[23];
    const float* W2 = (const float*)d_in[24], *b2 = (const float*)d_in[25],
               * A2 = (const float*)d_in[26], *B2 = (const float*)d_in[27];
    const float* g1 = (const float*)d_in[28], *be1 = (const float*)d_in[29];
    const float* g2 = (const float*)d_in[30], *be2 = (const float*)d_in[31];
    const float* fcW = (const float*)d_in[32], *fcb = (const float*)d_in[33];
    const float* fcA = (const float*)d_in[34], *fcBm = (const float*)d_in[35];

    const size_t ND = (size_t)NTOK * DSZ;

    // ---- workspace budget: pick the largest sequence-chunk that fits ------
    // fixed floats: x (ND) + weff_qkv (2304*768) + bias_qkv (2304, padded)
    //               + weff_o (768*768) + weff_f1 (3072*768) + weff_f2 (768*3072)
    //               + xm (64*768)
    const size_t WQKV_F = (size_t)QKVM * DSZ;
    const size_t BQKV_F = 2560;                  // 2304 padded
    const size_t WO_F   = (size_t)DSZ * DSZ;
    const size_t WF1_F  = (size_t)HIDSZ * DSZ;
    const size_t WF2_F  = (size_t)DSZ * HIDSZ;
    const size_t XM_F   = (size_t)BBATCH * DSZ;
    const size_t fixedF = ND + WQKV_F + BQKV_F + WO_F + WF1_F + WF2_F + XM_F;
    const size_t availF = ws_size / 4;

    int schunk = 2;
    const int cand[6] = {512, 256, 128, 64, 32, 16};
    for (int i = 0; i < 6; ++i) {
        size_t chunkF = (size_t)cand[i] * BBATCH * HIDSZ;
        if (fixedF + chunkF <= availF) { schunk = cand[i]; break; }
    }
    const int Nc = schunk * BBATCH;              // rows per chunk
    const int nchunk = SSEQ / schunk;
    const size_t chunkF = (size_t)Nc * HIDSZ;

    float* ws   = (float*)d_ws;
    float* x    = ws;                            // ND
    float* cbuf = x + ND;                        // chunk scratch: qkv (ldx 2304) / h (3072)
    float* wqkv = cbuf + chunkF;
    float* bqkv = wqkv + WQKV_F;
    float* wo   = bqkv + BQKV_F;
    float* wf1  = wo + WO_F;
    float* wf2  = wf1 + WF1_F;
    float* xm   = wf2 + WF2_F;

    embed_kernel<<<NTOK, 256, 0, stream>>>(tokens, embW, embA, embB, x);

    for (int l = 0; l < NL; ++l) {
        const size_t oDD = (size_t)l * DSZ * DSZ;
        const size_t oDH = (size_t)l * HIDSZ * DSZ;
        const size_t oRD = (size_t)l * RR * DSZ;
        const size_t oRH = (size_t)l * RR * HIDSZ;
        const size_t oDR = (size_t)l * DSZ * RR;
        const size_t oHR = (size_t)l * HIDSZ * RR;

        // effective weights (LoRA folded), once per layer
        weff_kernel<<<dim3(3, DSZ), 256, 0, stream>>>(Wq + oDD, Aq + oRD, Bq + oDR, wqkv, DSZ);
        weff_kernel<<<dim3(3, DSZ), 256, 0, stream>>>(Wk + oDD, Ak + oRD, Bk + oDR, wqkv + (size_t)DSZ * DSZ, DSZ);
        weff_kernel<<<dim3(3, DSZ), 256, 0, stream>>>(Wv + oDD, Av + oRD, Bv + oDR, wqkv + (size_t)2 * DSZ * DSZ, DSZ);
        biascat_kernel<<<dim3(3, 3), 256, 0, stream>>>(bq + (size_t)l * DSZ, bk + (size_t)l * DSZ, bv + (size_t)l * DSZ, bqkv);
        weff_kernel<<<dim3(3, DSZ), 256, 0, stream>>>(Wo + oDD, Ao + oRD, Bo + oDR, wo, DSZ);
        weff_kernel<<<dim3(3, HIDSZ), 256, 0, stream>>>(W1 + oDH, A1 + oRD, B1 + oHR, wf1, DSZ);
        weff_kernel<<<dim3(12, DSZ), 256, 0, stream>>>(W2 + oDH, A2 + oRH, B2 + oDR, wf2, HIDSZ);

        const float* bo_l = bo + (size_t)l * DSZ;
        const float* b1_l = b1 + (size_t)l * HIDSZ;
        const float* b2_l = b2 + (size_t)l * DSZ;

        for (int c = 0; c < nchunk; ++c) {
            float* xc = x + (size_t)c * Nc * DSZ;

            // QKV (stacked): (Nc x 768) @ (2304 x 768)^T -> cbuf (ldy=2304)
            gemm_kernel<false, false><<<dim3(Nc / BT, QKVM / BT), 256, 0, stream>>>(
                xc, wqkv, bqkv, cbuf, DSZ, QKVM, DSZ, QKVM);

            // attention over batch per (s', h); ao overwrites Q slot
            attn_kernel<<<schunk * HN, 256, 0, stream>>>(cbuf);

            // O projection, residual-added into x
            gemm_kernel<false, true><<<dim3(Nc / BT, DSZ / BT), 256, 0, stream>>>(
                cbuf, wo, bo_l, xc, DSZ, DSZ, QKVM, DSZ);
            ln_kernel<<<Nc, 256, 0, stream>>>(xc, g1 + (size_t)l * DSZ, be1 + (size_t)l * DSZ);

            // FF1 (relu) -> cbuf as h (ldy=3072); qkv dead by now
            gemm_kernel<true, false><<<dim3(Nc / BT, HIDSZ / BT), 256, 0, stream>>>(
                xc, wf1, b1_l, cbuf, DSZ, HIDSZ, DSZ, HIDSZ);

            // FF2, residual-added into x
            gemm_kernel<false, true><<<dim3(Nc / BT, DSZ / BT), 256, 0, stream>>>(
                cbuf, wf2, b2_l, xc, HIDSZ, DSZ, HIDSZ, DSZ);
            ln_kernel<<<Nc, 256, 0, stream>>>(xc, g2 + (size_t)l * DSZ, be2 + (size_t)l * DSZ);
        }
    }

    meanS_kernel<<<(BBATCH * DSZ) / 256, 256, 0, stream>>>(x, xm);
    fc_kernel<<<1, 128, 0, stream>>>(xm, fcW, fcb, fcA, fcBm, (float*)d_out);
}

// Round 3
// 2890.934 us; speedup vs baseline: 3.9822x; 3.9822x over previous
//
#include <hip/hip_runtime.h>
#include <hip/hip_bf16.h>

#define VSZ   32000
#define DSZ   768
#define HN    12
#define HIDSZ 3072
#define NL    2
#define CN    2
#define RR    8
#define SCALEF 2.0f
#define BBATCH 64
#define SSEQ  512
#define HDIM  64
#define NTOK  (BBATCH*SSEQ)   // 32768
#define QKVM  (3*DSZ)         // 2304 — stacked QKV output width

typedef __attribute__((ext_vector_type(8))) short bf16x8;   // 8 bf16 (4 VGPRs)
typedef __attribute__((ext_vector_type(4))) float floatx4;

// ---------------------------------------------------------------------------
// async global->LDS 16B (wave-uniform base + lane*16; our lane->lds mapping
// is constructed to match exactly)
// ---------------------------------------------------------------------------
__device__ __forceinline__ void gload16(const void* g, void* l) {
    __builtin_amdgcn_global_load_lds(
        (const __attribute__((address_space(1))) unsigned int*)g,
        (__attribute__((address_space(3))) unsigned int*)l, 16, 0, 0);
}

// ---------------------------------------------------------------------------
// Embedding: x fp32 + xb bf16
// ---------------------------------------------------------------------------
__global__ __launch_bounds__(256) void embed_kernel(
    const int* __restrict__ tokens, const float* __restrict__ embW,
    const float* __restrict__ embA, const float* __restrict__ embB,
    float* __restrict__ x, __hip_bfloat16* __restrict__ xb)
{
    int n = blockIdx.x;            // n = s*B + b
    int s = n / BBATCH, b = n % BBATCH;
    int tok = tokens[b * SSEQ + s];
    __shared__ float a[RR];
    if (threadIdx.x < RR) a[threadIdx.x] = embA[(size_t)threadIdx.x * VSZ + tok];
    __syncthreads();
    for (int d = threadIdx.x; d < DSZ; d += 256) {
        float val = embW[(size_t)tok * DSZ + d];
        float lo = 0.f;
        #pragma unroll
        for (int r = 0; r < RR; ++r) lo += a[r] * embB[d * RR + r];
        float v = val + SCALEF * lo;
        x[(size_t)n * DSZ + d] = v;
        xb[(size_t)n * DSZ + d] = __float2bfloat16(v);
    }
}

// ---------------------------------------------------------------------------
// Effective weight (LoRA folded) -> bf16.  grid = (K/256, M)
// ---------------------------------------------------------------------------
__global__ __launch_bounds__(256) void weff_kernel(
    const float* __restrict__ W, const float* __restrict__ A,
    const float* __restrict__ Bm, __hip_bfloat16* __restrict__ Weff, int K)
{
    int i = blockIdx.x * 256 + threadIdx.x;
    int o = blockIdx.y;
    float acc = W[(size_t)o * K + i];
    #pragma unroll
    for (int r = 0; r < RR; ++r)
        acc += SCALEF * Bm[o * RR + r] * A[(size_t)r * K + i];
    Weff[(size_t)o * K + i] = __float2bfloat16(acc);
}

__global__ __launch_bounds__(256) void biascat_kernel(
    const float* __restrict__ b0, const float* __restrict__ b1v,
    const float* __restrict__ b2v, float* __restrict__ out)
{
    int t = blockIdx.y * 256 + threadIdx.x;   // 0..767
    const float* src = (blockIdx.x == 0) ? b0 : (blockIdx.x == 1) ? b1v : b2v;
    out[blockIdx.x * DSZ + t] = src[t];
}

// ---------------------------------------------------------------------------
// bf16 MFMA GEMM: Y[n,m] = sum_k X[n,k]*W[m,k] + bias[m]
// X bf16 (row stride ldx), W bf16 (row stride K), Y fp32 or bf16 (stride ldy).
// 128x128 tile, BK=32, 256 thr = 4 waves (2x2), each wave 4x4 MFMA 16x16x32.
// ---------------------------------------------------------------------------
#define GT 128
#define GK 32

template<bool RELU, bool ADDTO, bool OUTBF>
__global__ __launch_bounds__(256) void mgemm_kernel(
    const __hip_bfloat16* __restrict__ X, const __hip_bfloat16* __restrict__ W,
    const float* __restrict__ bias, void* __restrict__ Yv,
    int K, int ldx, int ldy)
{
    __shared__ unsigned short Xs[GT * GK];   // [row][k] row-major, 64B rows
    __shared__ unsigned short Ws[GT * GK];
    const int t    = threadIdx.x;
    const int n0   = blockIdx.x * GT;
    const int m0   = blockIdx.y * GT;
    const int wv   = t >> 6;
    const int lane = t & 63;
    const int wr   = (wv >> 1) * 64;   // wave row offset in tile
    const int wc   = (wv & 1) * 64;    // wave col offset in tile
    const int fm   = lane & 15;        // fragment free index
    const int fq   = lane >> 4;        // quad 0..3

    floatx4 acc[4][4];
    #pragma unroll
    for (int i = 0; i < 4; ++i)
        #pragma unroll
        for (int j = 0; j < 4; ++j)
            acc[i][j] = (floatx4){0.f, 0.f, 0.f, 0.f};

    const unsigned short* Xg = (const unsigned short*)X + (size_t)n0 * ldx;
    const unsigned short* Wg = (const unsigned short*)W + (size_t)m0 * K;

    // staging: seg = it*256 + t; row = seg>>2; k8 = (seg&3)*8 elements
    const int sr0 = t >> 2, sk0 = (t & 3) * 8;

    for (int k0 = 0; k0 < K; k0 += GK) {
        __syncthreads();   // prior ds_reads done before overwrite
        #pragma unroll
        for (int it = 0; it < 2; ++it) {
            int row = sr0 + it * 64;
            int seg = (it * 256 + t) * 8;
            gload16(Xg + (size_t)row * ldx + k0 + sk0, &Xs[seg]);
            gload16(Wg + (size_t)row * K   + k0 + sk0, &Ws[seg]);
        }
        __syncthreads();   // compiler drains vmcnt before barrier

        bf16x8 af[4], bf[4];
        #pragma unroll
        for (int i = 0; i < 4; ++i) {
            af[i] = *(const bf16x8*)&Xs[(wr + i * 16 + fm) * GK + fq * 8];
            bf[i] = *(const bf16x8*)&Ws[(wc + i * 16 + fm) * GK + fq * 8];
        }
        #pragma unroll
        for (int i = 0; i < 4; ++i)
            #pragma unroll
            for (int j = 0; j < 4; ++j)
                acc[i][j] = __builtin_amdgcn_mfma_f32_16x16x32_bf16(
                    af[i], bf[j], acc[i][j], 0, 0, 0);
    }

    // epilogue: D row (token) = wr + i*16 + fq*4 + r ; D col (feat) = wc + j*16 + fm
    float* Yf = (float*)Yv;
    __hip_bfloat16* Yh = (__hip_bfloat16*)Yv;
    #pragma unroll
    for (int j = 0; j < 4; ++j) {
        int col = m0 + wc + j * 16 + fm;
        float bj = bias[col];
        #pragma unroll
        for (int i = 0; i < 4; ++i) {
            int row = n0 + wr + i * 16 + fq * 4;
            #pragma unroll
            for (int r = 0; r < 4; ++r) {
                float v = acc[i][j][r] + bj;
                if (RELU) v = fmaxf(v, 0.f);
                size_t off = (size_t)(row + r) * ldy + col;
                if (ADDTO)      Yf[off] += v;
                else if (OUTBF) Yh[off] = __float2bfloat16(v);
                else            Yf[off] = v;
            }
        }
    }
}

// ---------------------------------------------------------------------------
// Attention over the BATCH axis. qkv fp32 rows stride QKVM: [Q|K|V].
// Output bf16 -> aob (stride DSZ). grid = schunk*HN.
// ---------------------------------------------------------------------------
__global__ __launch_bounds__(256) void attn_kernel(
    const float* __restrict__ qkv, __hip_bfloat16* __restrict__ aob)
{
    __shared__ float Qs[64][65];   // reused for P after scores
    __shared__ float Ks[64][65];
    __shared__ float Vs[64][65];
    const int t = threadIdx.x;
    const int sp = blockIdx.x / HN;
    const int h  = blockIdx.x % HN;
    const size_t base  = (size_t)sp * BBATCH * QKVM + h * HDIM;
    const size_t obase = (size_t)sp * BBATCH * DSZ  + h * HDIM;

    #pragma unroll
    for (int i = 0; i < 16; ++i) {
        int e = i * 256 + t;
        int r = e >> 6, c = e & 63;
        size_t rowoff = base + (size_t)r * QKVM + c;
        Qs[r][c] = qkv[rowoff];
        Ks[r][c] = qkv[rowoff + DSZ];
        Vs[r][c] = qkv[rowoff + 2 * DSZ];
    }
    __syncthreads();

    const int br = t >> 2;
    const int c0 = (t & 3) * 16;
    float sc[16];
    #pragma unroll
    for (int cc = 0; cc < 16; ++cc) sc[cc] = 0.f;
    for (int d = 0; d < 64; ++d) {
        float qv = Qs[br][d];
        #pragma unroll
        for (int cc = 0; cc < 16; ++cc) sc[cc] += qv * Ks[c0 + cc][d];
    }
    __syncthreads();
    #pragma unroll
    for (int cc = 0; cc < 16; ++cc) Qs[br][c0 + cc] = sc[cc] * 0.125f;
    __syncthreads();

    if (t < 64) {
        float mx = -1e30f;
        for (int c = 0; c < 64; ++c) mx = fmaxf(mx, Qs[t][c]);
        float sum = 0.f;
        for (int c = 0; c < 64; ++c) { float e = __expf(Qs[t][c] - mx); Qs[t][c] = e; sum += e; }
        float inv = 1.f / sum;
        for (int c = 0; c < 64; ++c) Qs[t][c] *= inv;
    }
    __syncthreads();

    const int d0 = (t & 3) * 16;
    float ov[16];
    #pragma unroll
    for (int dd = 0; dd < 16; ++dd) ov[dd] = 0.f;
    for (int c = 0; c < 64; ++c) {
        float pv = Qs[br][c];
        #pragma unroll
        for (int dd = 0; dd < 16; ++dd) ov[dd] += pv * Vs[c][d0 + dd];
    }
    #pragma unroll
    for (int dd = 0; dd < 16; ++dd)
        aob[obase + (size_t)br * DSZ + d0 + dd] = __float2bfloat16(ov[dd]);
}

// ---------------------------------------------------------------------------
// In-place LayerNorm; also emits bf16 copy for the next GEMM.
// ---------------------------------------------------------------------------
__device__ __forceinline__ float block_sum256(float vsum, volatile float* red) {
    #pragma unroll
    for (int off = 32; off > 0; off >>= 1) vsum += __shfl_down(vsum, off, 64);
    if ((threadIdx.x & 63) == 0) red[threadIdx.x >> 6] = vsum;
    __syncthreads();
    return red[0] + red[1] + red[2] + red[3];
}

__global__ __launch_bounds__(256) void ln_kernel(
    float* __restrict__ x, __hip_bfloat16* __restrict__ xb,
    const float* __restrict__ g, const float* __restrict__ be)
{
    __shared__ float red1[4];
    __shared__ float red2[4];
    const int n = blockIdx.x;
    const int t = threadIdx.x;
    float* row = x + (size_t)n * DSZ;
    __hip_bfloat16* rowb = xb + (size_t)n * DSZ;
    float v0 = row[t], v1 = row[t + 256], v2 = row[t + 512];
    float total = block_sum256(v0 + v1 + v2, red1);
    float mean = total * (1.0f / DSZ);
    float d0 = v0 - mean, d1 = v1 - mean, d2 = v2 - mean;
    __syncthreads();
    float var = block_sum256(d0 * d0 + d1 * d1 + d2 * d2, red2) * (1.0f / DSZ);
    float rstd = rsqrtf(var + 1e-5f);
    float o0 = d0 * rstd * g[t]       + be[t];
    float o1 = d1 * rstd * g[t + 256] + be[t + 256];
    float o2 = d2 * rstd * g[t + 512] + be[t + 512];
    row[t] = o0; row[t + 256] = o1; row[t + 512] = o2;
    rowb[t]       = __float2bfloat16(o0);
    rowb[t + 256] = __float2bfloat16(o1);
    rowb[t + 512] = __float2bfloat16(o2);
}

// ---------------------------------------------------------------------------
__global__ __launch_bounds__(256) void meanS_kernel(
    const float* __restrict__ x, float* __restrict__ xm)
{
    int idx = blockIdx.x * 256 + threadIdx.x;   // over B*D, d fastest
    int b = idx / DSZ, d = idx % DSZ;
    float acc = 0.f;
    for (int s = 0; s < SSEQ; ++s)
        acc += x[((size_t)s * BBATCH + b) * DSZ + d];
    xm[idx] = acc * (1.0f / SSEQ);
}

__global__ __launch_bounds__(128) void fc_kernel(
    const float* __restrict__ xm, const float* __restrict__ fcW,
    const float* __restrict__ fcb, const float* __restrict__ fcA,
    const float* __restrict__ fcBm, float* __restrict__ out)
{
    int t = threadIdx.x;
    if (t >= BBATCH * CN) return;
    int b = t / CN, c = t % CN;
    float acc = fcb[c];
    float lora[RR];
    #pragma unroll
    for (int r = 0; r < RR; ++r) lora[r] = 0.f;
    for (int d = 0; d < DSZ; ++d) {
        float xv = xm[b * DSZ + d];
        acc += xv * fcW[c * DSZ + d];
        #pragma unroll
        for (int r = 0; r < RR; ++r) lora[r] += xv * fcA[r * DSZ + d];
    }
    float lo = 0.f;
    #pragma unroll
    for (int r = 0; r < RR; ++r) lo += lora[r] * fcBm[c * RR + r];
    out[b * CN + c] = acc + SCALEF * lo;
}

// ---------------------------------------------------------------------------
extern "C" void kernel_launch(void* const* d_in, const int* in_sizes, int n_in,
                              void* d_out, int out_size, void* d_ws, size_t ws_size,
                              hipStream_t stream) {
    const int*   tokens = (const int*)  d_in[0];
    const float* embW   = (const float*)d_in[1];
    const float* embA   = (const float*)d_in[2];
    const float* embB   = (const float*)d_in[3];
    const float* Wq = (const float*)d_in[4],  *bq = (const float*)d_in[5],
               * Aq = (const float*)d_in[6],  *Bq = (const float*)d_in[7];
    const float* Wk = (const float*)d_in[8],  *bk = (const float*)d_in[9],
               * Ak = (const float*)d_in[10], *Bk = (const float*)d_in[11];
    const float* Wv = (const float*)d_in[12], *bv = (const float*)d_in[13],
               * Av = (const float*)d_in[14], *Bv = (const float*)d_in[15];
    const float* Wo = (const float*)d_in[16], *bo = (const float*)d_in[17],
               * Ao = (const float*)d_in[18], *Bo = (const float*)d_in[19];
    const float* W1 = (const float*)d_in[20], *b1 = (const float*)d_in[21],
               * A1 = (const float*)d_in[22], *B1 = (const float*)d_in[23];
    const float* W2 = (const float*)d_in[24], *b2 = (const float*)d_in[25],
               * A2 = (const float*)d_in[26], *B2 = (const float*)d_in[27];
    const float* g1 = (const float*)d_in[28], *be1 = (const float*)d_in[29];
    const float* g2 = (const float*)d_in[30], *be2 = (const float*)d_in[31];
    const float* fcW = (const float*)d_in[32], *fcb = (const float*)d_in[33];
    const float* fcA = (const float*)d_in[34], *fcBm = (const float*)d_in[35];

    const size_t ND = (size_t)NTOK * DSZ;

    // ---- workspace layout (float units, everything padded to 4) ----------
    const size_t XB_F   = ND / 2;                       // bf16 x
    const size_t WQKV_F = (size_t)QKVM * DSZ / 2;       // bf16 stacked qkv W
    const size_t WO_F   = (size_t)DSZ * DSZ / 2;
    const size_t WF1_F  = (size_t)HIDSZ * DSZ / 2;
    const size_t WF2_F  = (size_t)DSZ * HIDSZ / 2;
    const size_t BQKV_F = 2304;
    const size_t XM_F   = (size_t)BBATCH * DSZ;
    const size_t fixedF = ND + XB_F + WQKV_F + WO_F + WF1_F + WF2_F + BQKV_F + XM_F;
    const size_t availF = ws_size / 4;

    int schunk = 2;
    const int cand[6] = {512, 256, 128, 64, 32, 16};
    for (int i = 0; i < 6; ++i) {
        // per-chunk: qkv fp32 (Nc*2304) + aob bf16 (Nc*768/2)
        size_t chunkF = (size_t)cand[i] * BBATCH * (QKVM + DSZ / 2);
        if (fixedF + chunkF <= availF) { schunk = cand[i]; break; }
    }
    const int Nc = schunk * BBATCH;
    const int nchunk = SSEQ / schunk;

    float* ws   = (float*)d_ws;
    float* x    = ws;                            // ND fp32
    float* p    = x + ND;
    __hip_bfloat16* xb = (__hip_bfloat16*)p;     p += XB_F;
    __hip_bfloat16* wqkvb = (__hip_bfloat16*)p;  p += WQKV_F;
    __hip_bfloat16* wob   = (__hip_bfloat16*)p;  p += WO_F;
    __hip_bfloat16* wf1b  = (__hip_bfloat16*)p;  p += WF1_F;
    __hip_bfloat16* wf2b  = (__hip_bfloat16*)p;  p += WF2_F;
    float* bqkv = p;                             p += BQKV_F;
    float* xm   = p;                             p += XM_F;
    float* cbuf = p;                             // Nc*2304 fp32 qkv / Nc*3072 bf16 h
    __hip_bfloat16* hb  = (__hip_bfloat16*)cbuf;
    __hip_bfloat16* aob = (__hip_bfloat16*)(cbuf + (size_t)Nc * QKVM);

    embed_kernel<<<NTOK, 256, 0, stream>>>(tokens, embW, embA, embB, x, xb);

    for (int l = 0; l < NL; ++l) {
        const size_t oDD = (size_t)l * DSZ * DSZ;
        const size_t oDH = (size_t)l * HIDSZ * DSZ;
        const size_t oRD = (size_t)l * RR * DSZ;
        const size_t oRH = (size_t)l * RR * HIDSZ;
        const size_t oDR = (size_t)l * DSZ * RR;
        const size_t oHR = (size_t)l * HIDSZ * RR;

        weff_kernel<<<dim3(3, DSZ), 256, 0, stream>>>(Wq + oDD, Aq + oRD, Bq + oDR, wqkvb, DSZ);
        weff_kernel<<<dim3(3, DSZ), 256, 0, stream>>>(Wk + oDD, Ak + oRD, Bk + oDR, wqkvb + (size_t)DSZ * DSZ, DSZ);
        weff_kernel<<<dim3(3, DSZ), 256, 0, stream>>>(Wv + oDD, Av + oRD, Bv + oDR, wqkvb + (size_t)2 * DSZ * DSZ, DSZ);
        biascat_kernel<<<dim3(3, 3), 256, 0, stream>>>(bq + (size_t)l * DSZ, bk + (size_t)l * DSZ, bv + (size_t)l * DSZ, bqkv);
        weff_kernel<<<dim3(3, DSZ), 256, 0, stream>>>(Wo + oDD, Ao + oRD, Bo + oDR, wob, DSZ);
        weff_kernel<<<dim3(3, HIDSZ), 256, 0, stream>>>(W1 + oDH, A1 + oRD, B1 + oHR, wf1b, DSZ);
        weff_kernel<<<dim3(12, DSZ), 256, 0, stream>>>(W2 + oDH, A2 + oRH, B2 + oDR, wf2b, HIDSZ);

        const float* bo_l = bo + (size_t)l * DSZ;
        const float* b1_l = b1 + (size_t)l * HIDSZ;
        const float* b2_l = b2 + (size_t)l * DSZ;

        for (int c = 0; c < nchunk; ++c) {
            float* xc = x + (size_t)c * Nc * DSZ;
            __hip_bfloat16* xcb = xb + (size_t)c * Nc * DSZ;

            // QKV stacked: (Nc x 768)bf16 @ (2304 x 768)bf16^T -> cbuf fp32
            mgemm_kernel<false, false, false><<<dim3(Nc / GT, QKVM / GT), 256, 0, stream>>>(
                xcb, wqkvb, bqkv, cbuf, DSZ, DSZ, QKVM);

            attn_kernel<<<schunk * HN, 256, 0, stream>>>(cbuf, aob);

            // O-proj: residual add into fp32 x
            mgemm_kernel<false, true, false><<<dim3(Nc / GT, DSZ / GT), 256, 0, stream>>>(
                aob, wob, bo_l, xc, DSZ, DSZ, DSZ);
            ln_kernel<<<Nc, 256, 0, stream>>>(xc, xcb, g1 + (size_t)l * DSZ, be1 + (size_t)l * DSZ);

            // FF1 (relu) -> bf16 h (qkv dead, reuse cbuf)
            mgemm_kernel<true, false, true><<<dim3(Nc / GT, HIDSZ / GT), 256, 0, stream>>>(
                xcb, wf1b, b1_l, hb, DSZ, DSZ, HIDSZ);

            // FF2: residual add into fp32 x
            mgemm_kernel<false, true, false><<<dim3(Nc / GT, DSZ / GT), 256, 0, stream>>>(
                hb, wf2b, b2_l, xc, HIDSZ, HIDSZ, DSZ);
            ln_kernel<<<Nc, 256, 0, stream>>>(xc, xcb, g2 + (size_t)l * DSZ, be2 + (size_t)l * DSZ);
        }
    }

    meanS_kernel<<<(BBATCH * DSZ) / 256, 256, 0, stream>>>(x, xm);
    fc_kernel<<<1, 128, 0, stream>>>(xm, fcW, fcb, fcA, fcBm, (float*)d_out);
}

// Round 5
// 2516.573 us; speedup vs baseline: 4.5746x; 1.1488x over previous
//
#include <hip/hip_runtime.h>
#include <hip/hip_bf16.h>

#define VSZ   32000
#define DSZ   768
#define HN    12
#define HIDSZ 3072
#define NL    2
#define CN    2
#define RR    8
#define SCALEF 2.0f
#define BBATCH 64
#define SSEQ  512
#define HDIM  64
#define NTOK  (BBATCH*SSEQ)   // 32768
#define QKVM  (3*DSZ)         // 2304 — stacked QKV output width

typedef __attribute__((ext_vector_type(8))) short bf16x8;   // 8 bf16 (4 VGPRs)
typedef __attribute__((ext_vector_type(4))) float floatx4;

__device__ __forceinline__ unsigned short f2bf_raw(float f) {
    __hip_bfloat16 h = __float2bfloat16(f);
    return __builtin_bit_cast(unsigned short, h);
}

// ---------------------------------------------------------------------------
__device__ __forceinline__ void gload16(const void* g, void* l) {
    __builtin_amdgcn_global_load_lds(
        (const __attribute__((address_space(1))) unsigned int*)g,
        (__attribute__((address_space(3))) unsigned int*)l, 16, 0, 0);
}

// ---------------------------------------------------------------------------
// Embedding: x fp32 + xb bf16
// ---------------------------------------------------------------------------
__global__ __launch_bounds__(256) void embed_kernel(
    const int* __restrict__ tokens, const float* __restrict__ embW,
    const float* __restrict__ embA, const float* __restrict__ embB,
    float* __restrict__ x, __hip_bfloat16* __restrict__ xb)
{
    int n = blockIdx.x;            // n = s*B + b
    int s = n / BBATCH, b = n % BBATCH;
    int tok = tokens[b * SSEQ + s];
    __shared__ float a[RR];
    if (threadIdx.x < RR) a[threadIdx.x] = embA[(size_t)threadIdx.x * VSZ + tok];
    __syncthreads();
    for (int d = threadIdx.x; d < DSZ; d += 256) {
        float val = embW[(size_t)tok * DSZ + d];
        float lo = 0.f;
        #pragma unroll
        for (int r = 0; r < RR; ++r) lo += a[r] * embB[d * RR + r];
        float v = val + SCALEF * lo;
        x[(size_t)n * DSZ + d] = v;
        xb[(size_t)n * DSZ + d] = __float2bfloat16(v);
    }
}

// ---------------------------------------------------------------------------
// Effective weight (LoRA folded) -> bf16.  grid = (K/256, M)
// ---------------------------------------------------------------------------
__global__ __launch_bounds__(256) void weff_kernel(
    const float* __restrict__ W, const float* __restrict__ A,
    const float* __restrict__ Bm, __hip_bfloat16* __restrict__ Weff, int K)
{
    int i = blockIdx.x * 256 + threadIdx.x;
    int o = blockIdx.y;
    float acc = W[(size_t)o * K + i];
    #pragma unroll
    for (int r = 0; r < RR; ++r)
        acc += SCALEF * Bm[o * RR + r] * A[(size_t)r * K + i];
    Weff[(size_t)o * K + i] = __float2bfloat16(acc);
}

__global__ __launch_bounds__(256) void biascat_kernel(
    const float* __restrict__ b0, const float* __restrict__ b1v,
    const float* __restrict__ b2v, float* __restrict__ out)
{
    int t = blockIdx.y * 256 + threadIdx.x;   // 0..767
    const float* src = (blockIdx.x == 0) ? b0 : (blockIdx.x == 1) ? b1v : b2v;
    out[blockIdx.x * DSZ + t] = src[t];
}

// ---------------------------------------------------------------------------
// bf16 MFMA GEMM: Y[n,m] = sum_k X[n,k]*W[m,k] + bias[m]
// 128x128 tile, BK=32, 256 thr = 4 waves (2x2), each wave 4x4 MFMA 16x16x32.
// ---------------------------------------------------------------------------
#define GT 128
#define GK 32

template<bool RELU, bool ADDTO, bool OUTBF>
__global__ __launch_bounds__(256) void mgemm_kernel(
    const __hip_bfloat16* __restrict__ X, const __hip_bfloat16* __restrict__ W,
    const float* __restrict__ bias, void* __restrict__ Yv,
    int K, int ldx, int ldy)
{
    __shared__ unsigned short Xs[GT * GK];   // [row][k] row-major, 64B rows
    __shared__ unsigned short Ws[GT * GK];
    const int t    = threadIdx.x;
    const int n0   = blockIdx.x * GT;
    const int m0   = blockIdx.y * GT;
    const int wv   = t >> 6;
    const int lane = t & 63;
    const int wr   = (wv >> 1) * 64;   // wave row offset in tile
    const int wc   = (wv & 1) * 64;    // wave col offset in tile
    const int fm   = lane & 15;        // fragment free index
    const int fq   = lane >> 4;        // quad 0..3

    floatx4 acc[4][4];
    #pragma unroll
    for (int i = 0; i < 4; ++i)
        #pragma unroll
        for (int j = 0; j < 4; ++j)
            acc[i][j] = (floatx4){0.f, 0.f, 0.f, 0.f};

    const unsigned short* Xg = (const unsigned short*)X + (size_t)n0 * ldx;
    const unsigned short* Wg = (const unsigned short*)W + (size_t)m0 * K;

    const int sr0 = t >> 2, sk0 = (t & 3) * 8;

    for (int k0 = 0; k0 < K; k0 += GK) {
        __syncthreads();
        #pragma unroll
        for (int it = 0; it < 2; ++it) {
            int row = sr0 + it * 64;
            int seg = (it * 256 + t) * 8;
            gload16(Xg + (size_t)row * ldx + k0 + sk0, &Xs[seg]);
            gload16(Wg + (size_t)row * K   + k0 + sk0, &Ws[seg]);
        }
        __syncthreads();

        bf16x8 af[4], bf[4];
        #pragma unroll
        for (int i = 0; i < 4; ++i) {
            af[i] = *(const bf16x8*)&Xs[(wr + i * 16 + fm) * GK + fq * 8];
            bf[i] = *(const bf16x8*)&Ws[(wc + i * 16 + fm) * GK + fq * 8];
        }
        #pragma unroll
        for (int i = 0; i < 4; ++i)
            #pragma unroll
            for (int j = 0; j < 4; ++j)
                acc[i][j] = __builtin_amdgcn_mfma_f32_16x16x32_bf16(
                    af[i], bf[j], acc[i][j], 0, 0, 0);
    }

    float* Yf = (float*)Yv;
    __hip_bfloat16* Yh = (__hip_bfloat16*)Yv;
    #pragma unroll
    for (int j = 0; j < 4; ++j) {
        int col = m0 + wc + j * 16 + fm;
        float bj = bias[col];
        #pragma unroll
        for (int i = 0; i < 4; ++i) {
            int row = n0 + wr + i * 16 + fq * 4;
            #pragma unroll
            for (int r = 0; r < 4; ++r) {
                float v = acc[i][j][r] + bj;
                if (RELU) v = fmaxf(v, 0.f);
                size_t off = (size_t)(row + r) * ldy + col;
                if (ADDTO)      Yf[off] += v;
                else if (OUTBF) Yh[off] = __float2bfloat16(v);
                else            Yf[off] = v;
            }
        }
    }
}

// ---------------------------------------------------------------------------
// MFMA attention over the BATCH axis. qkvb bf16 rows stride QKVM: [Q|K|V].
// Block = one (s',h), 4 waves; wave w owns score rows 16w..16w+15.
// Output bf16 -> aob (stride DSZ). grid = schunk*HN.
// ---------------------------------------------------------------------------
__global__ __launch_bounds__(256) void attn_kernel(
    const __hip_bfloat16* __restrict__ qkvb, __hip_bfloat16* __restrict__ aob)
{
    __shared__ __align__(16) unsigned short Vt[64][72];      // Vt[d][c] = V[c][d]
    __shared__ __align__(16) unsigned short Ps[4][16][72];   // per-wave P rows
    const int t    = threadIdx.x;
    const int wv   = t >> 6;
    const int lane = t & 63;
    const int fm   = lane & 15;
    const int fq   = lane >> 4;
    const int sp   = blockIdx.x / HN;
    const int h    = blockIdx.x % HN;
    const unsigned short* qg =
        (const unsigned short*)qkvb + (size_t)sp * BBATCH * QKVM + h * HDIM;

    // ---- stage V transposed: thread (c=lane, d0=wv*16) reads V[c][d0..d0+15]
    {
        const int c = lane, d0 = wv * 16;
        const unsigned short* vrow = qg + 2 * DSZ + (size_t)c * QKVM + d0;
        bf16x8 v0 = *(const bf16x8*)vrow;
        bf16x8 v1 = *(const bf16x8*)(vrow + 8);
        #pragma unroll
        for (int i = 0; i < 8; ++i) {
            Vt[d0 + i][c]     = (unsigned short)v0[i];
            Vt[d0 + 8 + i][c] = (unsigned short)v1[i];
        }
    }

    // ---- Q A-frags (own 16 rows) and K B-frags (all 64 cols), direct global
    const unsigned short* qrow = qg + (size_t)(wv * 16 + fm) * QKVM + fq * 8;
    bf16x8 af0 = *(const bf16x8*)qrow;
    bf16x8 af1 = *(const bf16x8*)(qrow + 32);
    bf16x8 bk0[4], bk1[4];
    #pragma unroll
    for (int jt = 0; jt < 4; ++jt) {
        const unsigned short* krow = qg + DSZ + (size_t)(jt * 16 + fm) * QKVM + fq * 8;
        bk0[jt] = *(const bf16x8*)krow;
        bk1[jt] = *(const bf16x8*)(krow + 32);
    }

    // ---- scores: 16x64 per wave, fp32 acc
    floatx4 sc[4];
    #pragma unroll
    for (int jt = 0; jt < 4; ++jt) sc[jt] = (floatx4){0.f, 0.f, 0.f, 0.f};
    #pragma unroll
    for (int jt = 0; jt < 4; ++jt) {
        sc[jt] = __builtin_amdgcn_mfma_f32_16x16x32_bf16(af0, bk0[jt], sc[jt], 0, 0, 0);
        sc[jt] = __builtin_amdgcn_mfma_f32_16x16x32_bf16(af1, bk1[jt], sc[jt], 0, 0, 0);
    }
    #pragma unroll
    for (int jt = 0; jt < 4; ++jt)
        #pragma unroll
        for (int r = 0; r < 4; ++r) sc[jt][r] *= 0.125f;

    // ---- softmax per row (row = fq*4+r, spread over 16 lanes x 4 jt)
    float pr[4][4];   // pr[jt][r] = softmax numerator
    #pragma unroll
    for (int r = 0; r < 4; ++r) {
        float m = fmaxf(fmaxf(sc[0][r], sc[1][r]), fmaxf(sc[2][r], sc[3][r]));
        #pragma unroll
        for (int msk = 1; msk < 16; msk <<= 1) m = fmaxf(m, __shfl_xor(m, msk, 64));
        float s = 0.f;
        #pragma unroll
        for (int jt = 0; jt < 4; ++jt) { pr[jt][r] = __expf(sc[jt][r] - m); s += pr[jt][r]; }
        #pragma unroll
        for (int msk = 1; msk < 16; msk <<= 1) s += __shfl_xor(s, msk, 64);
        float inv = 1.f / s;
        #pragma unroll
        for (int jt = 0; jt < 4; ++jt) pr[jt][r] *= inv;
    }

    // ---- P -> LDS (C-layout -> A-layout round trip), bf16
    #pragma unroll
    for (int jt = 0; jt < 4; ++jt)
        #pragma unroll
        for (int r = 0; r < 4; ++r)
            Ps[wv][fq * 4 + r][jt * 16 + fm] = f2bf_raw(pr[jt][r]);

    __syncthreads();   // Vt (cross-wave) ready; Ps is wave-local

    // ---- PV: A = P (own rows), B = Vt
    bf16x8 ap0 = *(const bf16x8*)&Ps[wv][fm][fq * 8];
    bf16x8 ap1 = *(const bf16x8*)&Ps[wv][fm][32 + fq * 8];
    floatx4 ov[4];
    #pragma unroll
    for (int jt = 0; jt < 4; ++jt) ov[jt] = (floatx4){0.f, 0.f, 0.f, 0.f};
    #pragma unroll
    for (int jt = 0; jt < 4; ++jt) {
        bf16x8 bv0 = *(const bf16x8*)&Vt[jt * 16 + fm][fq * 8];
        bf16x8 bv1 = *(const bf16x8*)&Vt[jt * 16 + fm][32 + fq * 8];
        ov[jt] = __builtin_amdgcn_mfma_f32_16x16x32_bf16(ap0, bv0, ov[jt], 0, 0, 0);
        ov[jt] = __builtin_amdgcn_mfma_f32_16x16x32_bf16(ap1, bv1, ov[jt], 0, 0, 0);
    }

    // ---- write O bf16: row b = 16wv + 4fq + r, col d = jt*16+fm
    __hip_bfloat16* obase = aob + ((size_t)sp * BBATCH + wv * 16 + fq * 4) * DSZ + h * HDIM;
    #pragma unroll
    for (int jt = 0; jt < 4; ++jt)
        #pragma unroll
        for (int r = 0; r < 4; ++r)
            obase[(size_t)r * DSZ + jt * 16 + fm] = __float2bfloat16(ov[jt][r]);
}

// ---------------------------------------------------------------------------
// In-place LayerNorm; also emits bf16 copy for the next GEMM.
// ---------------------------------------------------------------------------
__device__ __forceinline__ float block_sum256(float vsum, volatile float* red) {
    #pragma unroll
    for (int off = 32; off > 0; off >>= 1) vsum += __shfl_down(vsum, off, 64);
    if ((threadIdx.x & 63) == 0) red[threadIdx.x >> 6] = vsum;
    __syncthreads();
    return red[0] + red[1] + red[2] + red[3];
}

__global__ __launch_bounds__(256) void ln_kernel(
    float* __restrict__ x, __hip_bfloat16* __restrict__ xb,
    const float* __restrict__ g, const float* __restrict__ be)
{
    __shared__ float red1[4];
    __shared__ float red2[4];
    const int n = blockIdx.x;
    const int t = threadIdx.x;
    float* row = x + (size_t)n * DSZ;
    __hip_bfloat16* rowb = xb + (size_t)n * DSZ;
    float v0 = row[t], v1 = row[t + 256], v2 = row[t + 512];
    float total = block_sum256(v0 + v1 + v2, red1);
    float mean = total * (1.0f / DSZ);
    float d0 = v0 - mean, d1 = v1 - mean, d2 = v2 - mean;
    __syncthreads();
    float var = block_sum256(d0 * d0 + d1 * d1 + d2 * d2, red2) * (1.0f / DSZ);
    float rstd = rsqrtf(var + 1e-5f);
    float o0 = d0 * rstd * g[t]       + be[t];
    float o1 = d1 * rstd * g[t + 256] + be[t + 256];
    float o2 = d2 * rstd * g[t + 512] + be[t + 512];
    row[t] = o0; row[t + 256] = o1; row[t + 512] = o2;
    rowb[t]       = __float2bfloat16(o0);
    rowb[t + 256] = __float2bfloat16(o1);
    rowb[t + 512] = __float2bfloat16(o2);
}

// ---------------------------------------------------------------------------
__global__ __launch_bounds__(256) void meanS_kernel(
    const float* __restrict__ x, float* __restrict__ xm)
{
    int idx = blockIdx.x * 256 + threadIdx.x;   // over B*D, d fastest
    int b = idx / DSZ, d = idx % DSZ;
    float acc = 0.f;
    for (int s = 0; s < SSEQ; ++s)
        acc += x[((size_t)s * BBATCH + b) * DSZ + d];
    xm[idx] = acc * (1.0f / SSEQ);
}

__global__ __launch_bounds__(128) void fc_kernel(
    const float* __restrict__ xm, const float* __restrict__ fcW,
    const float* __restrict__ fcb, const float* __restrict__ fcA,
    const float* __restrict__ fcBm, float* __restrict__ out)
{
    int t = threadIdx.x;
    if (t >= BBATCH * CN) return;
    int b = t / CN, c = t % CN;
    float acc = fcb[c];
    float lora[RR];
    #pragma unroll
    for (int r = 0; r < RR; ++r) lora[r] = 0.f;
    for (int d = 0; d < DSZ; ++d) {
        float xv = xm[b * DSZ + d];
        acc += xv * fcW[c * DSZ + d];
        #pragma unroll
        for (int r = 0; r < RR; ++r) lora[r] += xv * fcA[r * DSZ + d];
    }
    float lo = 0.f;
    #pragma unroll
    for (int r = 0; r < RR; ++r) lo += lora[r] * fcBm[c * RR + r];
    out[b * CN + c] = acc + SCALEF * lo;
}

// ---------------------------------------------------------------------------
extern "C" void kernel_launch(void* const* d_in, const int* in_sizes, int n_in,
                              void* d_out, int out_size, void* d_ws, size_t ws_size,
                              hipStream_t stream) {
    const int*   tokens = (const int*)  d_in[0];
    const float* embW   = (const float*)d_in[1];
    const float* embA   = (const float*)d_in[2];
    const float* embB   = (const float*)d_in[3];
    const float* Wq = (const float*)d_in[4],  *bq = (const float*)d_in[5],
               * Aq = (const float*)d_in[6],  *Bq = (const float*)d_in[7];
    const float* Wk = (const float*)d_in[8],  *bk = (const float*)d_in[9],
               * Ak = (const float*)d_in[10], *Bk = (const float*)d_in[11];
    const float* Wv = (const float*)d_in[12], *bv = (const float*)d_in[13],
               * Av = (const float*)d_in[14], *Bv = (const float*)d_in[15];
    const float* Wo = (const float*)d_in[16], *bo = (const float*)d_in[17],
               * Ao = (const float*)d_in[18], *Bo = (const float*)d_in[19];
    const float* W1 = (const float*)d_in[20], *b1 = (const float*)d_in[21],
               * A1 = (const float*)d_in[22], *B1 = (const float*)d_in[23];
    const float* W2 = (const float*)d_in[24], *b2 = (const float*)d_in[25],
               * A2 = (const float*)d_in[26], *B2 = (const float*)d_in[27];
    const float* g1 = (const float*)d_in[28], *be1 = (const float*)d_in[29];
    const float* g2 = (const float*)d_in[30], *be2 = (const float*)d_in[31];
    const float* fcW = (const float*)d_in[32], *fcb = (const float*)d_in[33];
    const float* fcA = (const float*)d_in[34], *fcBm = (const float*)d_in[35];

    const size_t ND = (size_t)NTOK * DSZ;

    // ---- workspace layout (float units) ----------------------------------
    const size_t XB_F   = ND / 2;                       // bf16 x
    const size_t WQKV_F = (size_t)QKVM * DSZ / 2;       // bf16 stacked qkv W
    const size_t WO_F   = (size_t)DSZ * DSZ / 2;
    const size_t WF1_F  = (size_t)HIDSZ * DSZ / 2;
    const size_t WF2_F  = (size_t)DSZ * HIDSZ / 2;
    const size_t BQKV_F = 2304;
    const size_t XM_F   = (size_t)BBATCH * DSZ;
    const size_t fixedF = ND + XB_F + WQKV_F + WO_F + WF1_F + WF2_F + BQKV_F + XM_F;
    const size_t availF = ws_size / 4;

    int schunk = 2;
    const int cand[6] = {512, 256, 128, 64, 32, 16};
    for (int i = 0; i < 6; ++i) {
        // per-chunk: bf16 qkv (Nc*2304) + bf16 aob (Nc*768) == bf16 h (Nc*3072)
        size_t chunkF = (size_t)cand[i] * BBATCH * (HIDSZ / 2);
        if (fixedF + chunkF <= availF) { schunk = cand[i]; break; }
    }
    const int Nc = schunk * BBATCH;
    const int nchunk = SSEQ / schunk;

    float* ws   = (float*)d_ws;
    float* x    = ws;                            // ND fp32
    float* p    = x + ND;
    __hip_bfloat16* xb = (__hip_bfloat16*)p;     p += XB_F;
    __hip_bfloat16* wqkvb = (__hip_bfloat16*)p;  p += WQKV_F;
    __hip_bfloat16* wob   = (__hip_bfloat16*)p;  p += WO_F;
    __hip_bfloat16* wf1b  = (__hip_bfloat16*)p;  p += WF1_F;
    __hip_bfloat16* wf2b  = (__hip_bfloat16*)p;  p += WF2_F;
    float* bqkv = p;                             p += BQKV_F;
    float* xm   = p;                             p += XM_F;
    __hip_bfloat16* cb16 = (__hip_bfloat16*)p;   // chunk: qkvb|aob, later h
    __hip_bfloat16* qkvb = cb16;
    __hip_bfloat16* aob  = cb16 + (size_t)Nc * QKVM;
    __hip_bfloat16* hb   = cb16;

    embed_kernel<<<NTOK, 256, 0, stream>>>(tokens, embW, embA, embB, x, xb);

    for (int l = 0; l < NL; ++l) {
        const size_t oDD = (size_t)l * DSZ * DSZ;
        const size_t oDH = (size_t)l * HIDSZ * DSZ;
        const size_t oRD = (size_t)l * RR * DSZ;
        const size_t oRH = (size_t)l * RR * HIDSZ;
        const size_t oDR = (size_t)l * DSZ * RR;
        const size_t oHR = (size_t)l * HIDSZ * RR;

        weff_kernel<<<dim3(3, DSZ), 256, 0, stream>>>(Wq + oDD, Aq + oRD, Bq + oDR, wqkvb, DSZ);
        weff_kernel<<<dim3(3, DSZ), 256, 0, stream>>>(Wk + oDD, Ak + oRD, Bk + oDR, wqkvb + (size_t)DSZ * DSZ, DSZ);
        weff_kernel<<<dim3(3, DSZ), 256, 0, stream>>>(Wv + oDD, Av + oRD, Bv + oDR, wqkvb + (size_t)2 * DSZ * DSZ, DSZ);
        biascat_kernel<<<dim3(3, 3), 256, 0, stream>>>(bq + (size_t)l * DSZ, bk + (size_t)l * DSZ, bv + (size_t)l * DSZ, bqkv);
        weff_kernel<<<dim3(3, DSZ), 256, 0, stream>>>(Wo + oDD, Ao + oRD, Bo + oDR, wob, DSZ);
        weff_kernel<<<dim3(3, HIDSZ), 256, 0, stream>>>(W1 + oDH, A1 + oRD, B1 + oHR, wf1b, DSZ);
        weff_kernel<<<dim3(12, DSZ), 256, 0, stream>>>(W2 + oDH, A2 + oRH, B2 + oDR, wf2b, HIDSZ);

        const float* bo_l = bo + (size_t)l * DSZ;
        const float* b1_l = b1 + (size_t)l * HIDSZ;
        const float* b2_l = b2 + (size_t)l * DSZ;

        for (int c = 0; c < nchunk; ++c) {
            float* xc = x + (size_t)c * Nc * DSZ;
            __hip_bfloat16* xcb = xb + (size_t)c * Nc * DSZ;

            // QKV stacked: (Nc x 768)bf16 @ (2304 x 768)bf16^T -> bf16 qkvb
            mgemm_kernel<false, false, true><<<dim3(Nc / GT, QKVM / GT), 256, 0, stream>>>(
                xcb, wqkvb, bqkv, qkvb, DSZ, DSZ, QKVM);

            attn_kernel<<<schunk * HN, 256, 0, stream>>>(qkvb, aob);

            // O-proj: residual add into fp32 x
            mgemm_kernel<false, true, false><<<dim3(Nc / GT, DSZ / GT), 256, 0, stream>>>(
                aob, wob, bo_l, xc, DSZ, DSZ, DSZ);
            ln_kernel<<<Nc, 256, 0, stream>>>(xc, xcb, g1 + (size_t)l * DSZ, be1 + (size_t)l * DSZ);

            // FF1 (relu) -> bf16 h (qkv/aob dead, reuse chunk buffer)
            mgemm_kernel<true, false, true><<<dim3(Nc / GT, HIDSZ / GT), 256, 0, stream>>>(
                xcb, wf1b, b1_l, hb, DSZ, DSZ, HIDSZ);

            // FF2: residual add into fp32 x
            mgemm_kernel<false, true, false><<<dim3(Nc / GT, DSZ / GT), 256, 0, stream>>>(
                hb, wf2b, b2_l, xc, HIDSZ, HIDSZ, DSZ);
            ln_kernel<<<Nc, 256, 0, stream>>>(xc, xcb, g2 + (size_t)l * DSZ, be2 + (size_t)l * DSZ);
        }
    }

    meanS_kernel<<<(BBATCH * DSZ) / 256, 256, 0, stream>>>(x, xm);
    fc_kernel<<<1, 128, 0, stream>>>(xm, fcW, fcb, fcA, fcBm, (float*)d_out);
}

// Round 6
// 2258.622 us; speedup vs baseline: 5.0970x; 1.1142x over previous
//
#include <hip/hip_runtime.h>
#include <hip/hip_bf16.h>

#define VSZ   32000
#define DSZ   768
#define HN    12
#define HIDSZ 3072
#define NL    2
#define CN    2
#define RR    8
#define SCALEF 2.0f
#define BBATCH 64
#define SSEQ  512
#define HDIM  64
#define NTOK  (BBATCH*SSEQ)   // 32768
#define QKVM  (3*DSZ)         // 2304 — stacked QKV output width

typedef __attribute__((ext_vector_type(8))) short bf16x8;   // 8 bf16 (4 VGPRs)
typedef __attribute__((ext_vector_type(4))) float floatx4;

__device__ __forceinline__ unsigned short f2bf_raw(float f) {
    __hip_bfloat16 h = __float2bfloat16(f);
    return __builtin_bit_cast(unsigned short, h);
}
__device__ __forceinline__ float bf2f(__hip_bfloat16 h) {
    return __bfloat162float(h);
}

// ---------------------------------------------------------------------------
__device__ __forceinline__ void gload16(const void* g, void* l) {
    __builtin_amdgcn_global_load_lds(
        (const __attribute__((address_space(1))) unsigned int*)g,
        (__attribute__((address_space(3))) unsigned int*)l, 16, 0, 0);
}

// ---------------------------------------------------------------------------
// Embedding -> bf16 x
// ---------------------------------------------------------------------------
__global__ __launch_bounds__(256) void embed_kernel(
    const int* __restrict__ tokens, const float* __restrict__ embW,
    const float* __restrict__ embA, const float* __restrict__ embB,
    __hip_bfloat16* __restrict__ xb)
{
    int n = blockIdx.x;            // n = s*B + b
    int s = n / BBATCH, b = n % BBATCH;
    int tok = tokens[b * SSEQ + s];
    __shared__ float a[RR];
    if (threadIdx.x < RR) a[threadIdx.x] = embA[(size_t)threadIdx.x * VSZ + tok];
    __syncthreads();
    for (int d = threadIdx.x; d < DSZ; d += 256) {
        float val = embW[(size_t)tok * DSZ + d];
        float lo = 0.f;
        #pragma unroll
        for (int r = 0; r < RR; ++r) lo += a[r] * embB[d * RR + r];
        xb[(size_t)n * DSZ + d] = __float2bfloat16(val + SCALEF * lo);
    }
}

// ---------------------------------------------------------------------------
// Effective weight (LoRA folded) -> bf16.  grid = (K/256, M)
// ---------------------------------------------------------------------------
__global__ __launch_bounds__(256) void weff_kernel(
    const float* __restrict__ W, const float* __restrict__ A,
    const float* __restrict__ Bm, __hip_bfloat16* __restrict__ Weff, int K)
{
    int i = blockIdx.x * 256 + threadIdx.x;
    int o = blockIdx.y;
    float acc = W[(size_t)o * K + i];
    #pragma unroll
    for (int r = 0; r < RR; ++r)
        acc += SCALEF * Bm[o * RR + r] * A[(size_t)r * K + i];
    Weff[(size_t)o * K + i] = __float2bfloat16(acc);
}

__global__ __launch_bounds__(256) void biascat_kernel(
    const float* __restrict__ b0, const float* __restrict__ b1v,
    const float* __restrict__ b2v, float* __restrict__ out)
{
    int t = blockIdx.y * 256 + threadIdx.x;   // 0..767
    const float* src = (blockIdx.x == 0) ? b0 : (blockIdx.x == 1) ? b1v : b2v;
    out[blockIdx.x * DSZ + t] = src[t];
}

// ---------------------------------------------------------------------------
// bf16 MFMA GEMM: Y[n,m] = bf16( X@W^T + bias (+ res) ), optional relu.
// 128x128 tile, BK=32, 256 thr = 4 waves (2x2), each wave 4x4 MFMA 16x16x32.
// ---------------------------------------------------------------------------
#define GT 128
#define GK 32

template<bool RELU, bool ADDRES>
__global__ __launch_bounds__(256) void mgemm_kernel(
    const __hip_bfloat16* __restrict__ X, const __hip_bfloat16* __restrict__ W,
    const float* __restrict__ bias, const __hip_bfloat16* __restrict__ res,
    __hip_bfloat16* __restrict__ Y, int K, int ldx, int ldy)
{
    __shared__ unsigned short Xs[GT * GK];   // [row][k] row-major, 64B rows
    __shared__ unsigned short Ws[GT * GK];
    const int t    = threadIdx.x;
    const int n0   = blockIdx.x * GT;
    const int m0   = blockIdx.y * GT;
    const int wv   = t >> 6;
    const int lane = t & 63;
    const int wr   = (wv >> 1) * 64;   // wave row offset in tile
    const int wc   = (wv & 1) * 64;    // wave col offset in tile
    const int fm   = lane & 15;        // fragment free index
    const int fq   = lane >> 4;        // quad 0..3

    floatx4 acc[4][4];
    #pragma unroll
    for (int i = 0; i < 4; ++i)
        #pragma unroll
        for (int j = 0; j < 4; ++j)
            acc[i][j] = (floatx4){0.f, 0.f, 0.f, 0.f};

    const unsigned short* Xg = (const unsigned short*)X + (size_t)n0 * ldx;
    const unsigned short* Wg = (const unsigned short*)W + (size_t)m0 * K;

    const int sr0 = t >> 2, sk0 = (t & 3) * 8;

    for (int k0 = 0; k0 < K; k0 += GK) {
        __syncthreads();
        #pragma unroll
        for (int it = 0; it < 2; ++it) {
            int row = sr0 + it * 64;
            int seg = (it * 256 + t) * 8;
            gload16(Xg + (size_t)row * ldx + k0 + sk0, &Xs[seg]);
            gload16(Wg + (size_t)row * K   + k0 + sk0, &Ws[seg]);
        }
        __syncthreads();

        bf16x8 af[4], bf[4];
        #pragma unroll
        for (int i = 0; i < 4; ++i) {
            af[i] = *(const bf16x8*)&Xs[(wr + i * 16 + fm) * GK + fq * 8];
            bf[i] = *(const bf16x8*)&Ws[(wc + i * 16 + fm) * GK + fq * 8];
        }
        #pragma unroll
        for (int i = 0; i < 4; ++i)
            #pragma unroll
            for (int j = 0; j < 4; ++j)
                acc[i][j] = __builtin_amdgcn_mfma_f32_16x16x32_bf16(
                    af[i], bf[j], acc[i][j], 0, 0, 0);
    }

    // epilogue: D row (token) = wr + i*16 + fq*4 + r ; D col (feat) = wc + j*16 + fm
    #pragma unroll
    for (int j = 0; j < 4; ++j) {
        int col = m0 + wc + j * 16 + fm;
        float bj = bias[col];
        #pragma unroll
        for (int i = 0; i < 4; ++i) {
            int row = n0 + wr + i * 16 + fq * 4;
            #pragma unroll
            for (int r = 0; r < 4; ++r) {
                float v = acc[i][j][r] + bj;
                if (RELU) v = fmaxf(v, 0.f);
                size_t off = (size_t)(row + r) * ldy + col;
                if (ADDRES) v += bf2f(res[off]);
                Y[off] = __float2bfloat16(v);
            }
        }
    }
}

// ---------------------------------------------------------------------------
// MFMA attention over the BATCH axis. qkvb bf16 rows stride QKVM: [Q|K|V].
// Block = one (s',h), 4 waves; wave w owns score rows 16w..16w+15.
// Output bf16 -> aob (stride DSZ). grid = schunk*HN.
// ---------------------------------------------------------------------------
__global__ __launch_bounds__(256) void attn_kernel(
    const __hip_bfloat16* __restrict__ qkvb, __hip_bfloat16* __restrict__ aob)
{
    __shared__ __align__(16) unsigned short Vt[64][72];      // Vt[d][c] = V[c][d]
    __shared__ __align__(16) unsigned short Ps[4][16][72];   // per-wave P rows
    const int t    = threadIdx.x;
    const int wv   = t >> 6;
    const int lane = t & 63;
    const int fm   = lane & 15;
    const int fq   = lane >> 4;
    const int sp   = blockIdx.x / HN;
    const int h    = blockIdx.x % HN;
    const unsigned short* qg =
        (const unsigned short*)qkvb + (size_t)sp * BBATCH * QKVM + h * HDIM;

    // ---- stage V transposed: thread (c=lane, d0=wv*16) reads V[c][d0..d0+15]
    {
        const int c = lane, d0 = wv * 16;
        const unsigned short* vrow = qg + 2 * DSZ + (size_t)c * QKVM + d0;
        bf16x8 v0 = *(const bf16x8*)vrow;
        bf16x8 v1 = *(const bf16x8*)(vrow + 8);
        #pragma unroll
        for (int i = 0; i < 8; ++i) {
            Vt[d0 + i][c]     = (unsigned short)v0[i];
            Vt[d0 + 8 + i][c] = (unsigned short)v1[i];
        }
    }

    // ---- Q A-frags (own 16 rows) and K B-frags (all 64 cols), direct global
    const unsigned short* qrow = qg + (size_t)(wv * 16 + fm) * QKVM + fq * 8;
    bf16x8 af0 = *(const bf16x8*)qrow;
    bf16x8 af1 = *(const bf16x8*)(qrow + 32);
    bf16x8 bk0[4], bk1[4];
    #pragma unroll
    for (int jt = 0; jt < 4; ++jt) {
        const unsigned short* krow = qg + DSZ + (size_t)(jt * 16 + fm) * QKVM + fq * 8;
        bk0[jt] = *(const bf16x8*)krow;
        bk1[jt] = *(const bf16x8*)(krow + 32);
    }

    // ---- scores: 16x64 per wave, fp32 acc
    floatx4 sc[4];
    #pragma unroll
    for (int jt = 0; jt < 4; ++jt) sc[jt] = (floatx4){0.f, 0.f, 0.f, 0.f};
    #pragma unroll
    for (int jt = 0; jt < 4; ++jt) {
        sc[jt] = __builtin_amdgcn_mfma_f32_16x16x32_bf16(af0, bk0[jt], sc[jt], 0, 0, 0);
        sc[jt] = __builtin_amdgcn_mfma_f32_16x16x32_bf16(af1, bk1[jt], sc[jt], 0, 0, 0);
    }
    #pragma unroll
    for (int jt = 0; jt < 4; ++jt)
        #pragma unroll
        for (int r = 0; r < 4; ++r) sc[jt][r] *= 0.125f;

    // ---- softmax per row (row = fq*4+r, spread over 16 lanes x 4 jt)
    float pr[4][4];
    #pragma unroll
    for (int r = 0; r < 4; ++r) {
        float m = fmaxf(fmaxf(sc[0][r], sc[1][r]), fmaxf(sc[2][r], sc[3][r]));
        #pragma unroll
        for (int msk = 1; msk < 16; msk <<= 1) m = fmaxf(m, __shfl_xor(m, msk, 64));
        float s = 0.f;
        #pragma unroll
        for (int jt = 0; jt < 4; ++jt) { pr[jt][r] = __expf(sc[jt][r] - m); s += pr[jt][r]; }
        #pragma unroll
        for (int msk = 1; msk < 16; msk <<= 1) s += __shfl_xor(s, msk, 64);
        float inv = 1.f / s;
        #pragma unroll
        for (int jt = 0; jt < 4; ++jt) pr[jt][r] *= inv;
    }

    // ---- P -> LDS (C-layout -> A-layout round trip), bf16
    #pragma unroll
    for (int jt = 0; jt < 4; ++jt)
        #pragma unroll
        for (int r = 0; r < 4; ++r)
            Ps[wv][fq * 4 + r][jt * 16 + fm] = f2bf_raw(pr[jt][r]);

    __syncthreads();   // Vt (cross-wave) ready; Ps is wave-local

    // ---- PV: A = P (own rows), B = Vt
    bf16x8 ap0 = *(const bf16x8*)&Ps[wv][fm][fq * 8];
    bf16x8 ap1 = *(const bf16x8*)&Ps[wv][fm][32 + fq * 8];
    floatx4 ov[4];
    #pragma unroll
    for (int jt = 0; jt < 4; ++jt) ov[jt] = (floatx4){0.f, 0.f, 0.f, 0.f};
    #pragma unroll
    for (int jt = 0; jt < 4; ++jt) {
        bf16x8 bv0 = *(const bf16x8*)&Vt[jt * 16 + fm][fq * 8];
        bf16x8 bv1 = *(const bf16x8*)&Vt[jt * 16 + fm][32 + fq * 8];
        ov[jt] = __builtin_amdgcn_mfma_f32_16x16x32_bf16(ap0, bv0, ov[jt], 0, 0, 0);
        ov[jt] = __builtin_amdgcn_mfma_f32_16x16x32_bf16(ap1, bv1, ov[jt], 0, 0, 0);
    }

    // ---- write O bf16: row b = 16wv + 4fq + r, col d = jt*16+fm
    __hip_bfloat16* obase = aob + ((size_t)sp * BBATCH + wv * 16 + fq * 4) * DSZ + h * HDIM;
    #pragma unroll
    for (int jt = 0; jt < 4; ++jt)
        #pragma unroll
        for (int r = 0; r < 4; ++r)
            obase[(size_t)r * DSZ + jt * 16 + fm] = __float2bfloat16(ov[jt][r]);
}

// ---------------------------------------------------------------------------
// LayerNorm: src bf16 -> dst bf16 (separate buffers), fp32 stats.
// ---------------------------------------------------------------------------
__device__ __forceinline__ float block_sum256(float vsum, volatile float* red) {
    #pragma unroll
    for (int off = 32; off > 0; off >>= 1) vsum += __shfl_down(vsum, off, 64);
    if ((threadIdx.x & 63) == 0) red[threadIdx.x >> 6] = vsum;
    __syncthreads();
    return red[0] + red[1] + red[2] + red[3];
}

__global__ __launch_bounds__(256) void ln_kernel(
    const __hip_bfloat16* __restrict__ src, __hip_bfloat16* __restrict__ dst,
    const float* __restrict__ g, const float* __restrict__ be)
{
    __shared__ float red1[4];
    __shared__ float red2[4];
    const int n = blockIdx.x;
    const int t = threadIdx.x;
    const __hip_bfloat16* row = src + (size_t)n * DSZ;
    __hip_bfloat16* orow = dst + (size_t)n * DSZ;
    float v0 = bf2f(row[t]), v1 = bf2f(row[t + 256]), v2 = bf2f(row[t + 512]);
    float total = block_sum256(v0 + v1 + v2, red1);
    float mean = total * (1.0f / DSZ);
    float d0 = v0 - mean, d1 = v1 - mean, d2 = v2 - mean;
    __syncthreads();
    float var = block_sum256(d0 * d0 + d1 * d1 + d2 * d2, red2) * (1.0f / DSZ);
    float rstd = rsqrtf(var + 1e-5f);
    orow[t]       = __float2bfloat16(d0 * rstd * g[t]       + be[t]);
    orow[t + 256] = __float2bfloat16(d1 * rstd * g[t + 256] + be[t + 256]);
    orow[t + 512] = __float2bfloat16(d2 * rstd * g[t + 512] + be[t + 512]);
}

// ---------------------------------------------------------------------------
__global__ __launch_bounds__(256) void meanS_kernel(
    const __hip_bfloat16* __restrict__ x, float* __restrict__ xm)
{
    int idx = blockIdx.x * 256 + threadIdx.x;   // over B*D, d fastest
    int b = idx / DSZ, d = idx % DSZ;
    float acc = 0.f;
    for (int s = 0; s < SSEQ; ++s)
        acc += bf2f(x[((size_t)s * BBATCH + b) * DSZ + d]);
    xm[idx] = acc * (1.0f / SSEQ);
}

__global__ __launch_bounds__(128) void fc_kernel(
    const float* __restrict__ xm, const float* __restrict__ fcW,
    const float* __restrict__ fcb, const float* __restrict__ fcA,
    const float* __restrict__ fcBm, float* __restrict__ out)
{
    int t = threadIdx.x;
    if (t >= BBATCH * CN) return;
    int b = t / CN, c = t % CN;
    float acc = fcb[c];
    float lora[RR];
    #pragma unroll
    for (int r = 0; r < RR; ++r) lora[r] = 0.f;
    for (int d = 0; d < DSZ; ++d) {
        float xv = xm[b * DSZ + d];
        acc += xv * fcW[c * DSZ + d];
        #pragma unroll
        for (int r = 0; r < RR; ++r) lora[r] += xv * fcA[r * DSZ + d];
    }
    float lo = 0.f;
    #pragma unroll
    for (int r = 0; r < RR; ++r) lo += lora[r] * fcBm[c * RR + r];
    out[b * CN + c] = acc + SCALEF * lo;
}

// ---------------------------------------------------------------------------
extern "C" void kernel_launch(void* const* d_in, const int* in_sizes, int n_in,
                              void* d_out, int out_size, void* d_ws, size_t ws_size,
                              hipStream_t stream) {
    const int*   tokens = (const int*)  d_in[0];
    const float* embW   = (const float*)d_in[1];
    const float* embA   = (const float*)d_in[2];
    const float* embB   = (const float*)d_in[3];
    const float* Wq = (const float*)d_in[4],  *bq = (const float*)d_in[5],
               * Aq = (const float*)d_in[6],  *Bq = (const float*)d_in[7];
    const float* Wk = (const float*)d_in[8],  *bk = (const float*)d_in[9],
               * Ak = (const float*)d_in[10], *Bk = (const float*)d_in[11];
    const float* Wv = (const float*)d_in[12], *bv = (const float*)d_in[13],
               * Av = (const float*)d_in[14], *Bv = (const float*)d_in[15];
    const float* Wo = (const float*)d_in[16], *bo = (const float*)d_in[17],
               * Ao = (const float*)d_in[18], *Bo = (const float*)d_in[19];
    const float* W1 = (const float*)d_in[20], *b1 = (const float*)d_in[21],
               * A1 = (const float*)d_in[22], *B1 = (const float*)d_in[23];
    const float* W2 = (const float*)d_in[24], *b2 = (const float*)d_in[25],
               * A2 = (const float*)d_in[26], *B2 = (const float*)d_in[27];
    const float* g1 = (const float*)d_in[28], *be1 = (const float*)d_in[29];
    const float* g2 = (const float*)d_in[30], *be2 = (const float*)d_in[31];
    const float* fcW = (const float*)d_in[32], *fcb = (const float*)d_in[33];
    const float* fcA = (const float*)d_in[34], *fcBm = (const float*)d_in[35];

    const size_t ND = (size_t)NTOK * DSZ;

    // ---- workspace layout (float units; all sections multiple of 4) ------
    const size_t X_F    = ND / 2;                       // bf16 x (LN out / residual base)
    const size_t XT_F   = ND / 2;                       // bf16 xt (pre-LN sum)
    const size_t WQKV_F = (size_t)QKVM * DSZ / 2;
    const size_t WO_F   = (size_t)DSZ * DSZ / 2;
    const size_t WF1_F  = (size_t)HIDSZ * DSZ / 2;
    const size_t WF2_F  = (size_t)DSZ * HIDSZ / 2;
    const size_t BQKV_F = 2304;
    const size_t XM_F   = (size_t)BBATCH * DSZ;
    const size_t fixedF = X_F + XT_F + WQKV_F + WO_F + WF1_F + WF2_F + BQKV_F + XM_F;
    const size_t availF = ws_size / 4;

    int schunk = 2;
    const int cand[6] = {512, 256, 128, 64, 32, 16};
    for (int i = 0; i < 6; ++i) {
        // per-chunk: bf16 qkv (Nc*2304) + bf16 aob (Nc*768) == bf16 h (Nc*3072)
        size_t chunkF = (size_t)cand[i] * BBATCH * (HIDSZ / 2);
        if (fixedF + chunkF <= availF) { schunk = cand[i]; break; }
    }
    const int Nc = schunk * BBATCH;
    const int nchunk = SSEQ / schunk;

    float* p = (float*)d_ws;
    __hip_bfloat16* x  = (__hip_bfloat16*)p;     p += X_F;
    __hip_bfloat16* xt = (__hip_bfloat16*)p;     p += XT_F;
    __hip_bfloat16* wqkvb = (__hip_bfloat16*)p;  p += WQKV_F;
    __hip_bfloat16* wob   = (__hip_bfloat16*)p;  p += WO_F;
    __hip_bfloat16* wf1b  = (__hip_bfloat16*)p;  p += WF1_F;
    __hip_bfloat16* wf2b  = (__hip_bfloat16*)p;  p += WF2_F;
    float* bqkv = p;                             p += BQKV_F;
    float* xm   = p;                             p += XM_F;
    __hip_bfloat16* cb16 = (__hip_bfloat16*)p;   // chunk: qkvb|aob, later h
    __hip_bfloat16* qkvb = cb16;
    __hip_bfloat16* aob  = cb16 + (size_t)Nc * QKVM;
    __hip_bfloat16* hb   = cb16;

    embed_kernel<<<NTOK, 256, 0, stream>>>(tokens, embW, embA, embB, x);

    for (int l = 0; l < NL; ++l) {
        const size_t oDD = (size_t)l * DSZ * DSZ;
        const size_t oDH = (size_t)l * HIDSZ * DSZ;
        const size_t oRD = (size_t)l * RR * DSZ;
        const size_t oRH = (size_t)l * RR * HIDSZ;
        const size_t oDR = (size_t)l * DSZ * RR;
        const size_t oHR = (size_t)l * HIDSZ * RR;

        weff_kernel<<<dim3(3, DSZ), 256, 0, stream>>>(Wq + oDD, Aq + oRD, Bq + oDR, wqkvb, DSZ);
        weff_kernel<<<dim3(3, DSZ), 256, 0, stream>>>(Wk + oDD, Ak + oRD, Bk + oDR, wqkvb + (size_t)DSZ * DSZ, DSZ);
        weff_kernel<<<dim3(3, DSZ), 256, 0, stream>>>(Wv + oDD, Av + oRD, Bv + oDR, wqkvb + (size_t)2 * DSZ * DSZ, DSZ);
        biascat_kernel<<<dim3(3, 3), 256, 0, stream>>>(bq + (size_t)l * DSZ, bk + (size_t)l * DSZ, bv + (size_t)l * DSZ, bqkv);
        weff_kernel<<<dim3(3, DSZ), 256, 0, stream>>>(Wo + oDD, Ao + oRD, Bo + oDR, wob, DSZ);
        weff_kernel<<<dim3(3, HIDSZ), 256, 0, stream>>>(W1 + oDH, A1 + oRD, B1 + oHR, wf1b, DSZ);
        weff_kernel<<<dim3(12, DSZ), 256, 0, stream>>>(W2 + oDH, A2 + oRH, B2 + oDR, wf2b, HIDSZ);

        const float* bo_l = bo + (size_t)l * DSZ;
        const float* b1_l = b1 + (size_t)l * HIDSZ;
        const float* b2_l = b2 + (size_t)l * DSZ;

        for (int c = 0; c < nchunk; ++c) {
            __hip_bfloat16* xc  = x  + (size_t)c * Nc * DSZ;
            __hip_bfloat16* xtc = xt + (size_t)c * Nc * DSZ;

            // QKV stacked: (Nc x 768) @ (2304 x 768)^T -> bf16 qkvb
            mgemm_kernel<false, false><<<dim3(Nc / GT, QKVM / GT), 256, 0, stream>>>(
                xc, wqkvb, bqkv, nullptr, qkvb, DSZ, DSZ, QKVM);

            attn_kernel<<<schunk * HN, 256, 0, stream>>>(qkvb, aob);

            // O-proj + residual(x) -> xt, then LN1: xt -> x
            mgemm_kernel<false, true><<<dim3(Nc / GT, DSZ / GT), 256, 0, stream>>>(
                aob, wob, bo_l, xc, xtc, DSZ, DSZ, DSZ);
            ln_kernel<<<Nc, 256, 0, stream>>>(xtc, xc, g1 + (size_t)l * DSZ, be1 + (size_t)l * DSZ);

            // FF1 (relu) -> bf16 h (qkv/aob dead, reuse chunk buffer)
            mgemm_kernel<true, false><<<dim3(Nc / GT, HIDSZ / GT), 256, 0, stream>>>(
                xc, wf1b, b1_l, nullptr, hb, DSZ, DSZ, HIDSZ);

            // FF2 + residual(x) -> xt, then LN2: xt -> x
            mgemm_kernel<false, true><<<dim3(Nc / GT, DSZ / GT), 256, 0, stream>>>(
                hb, wf2b, b2_l, xc, xtc, HIDSZ, HIDSZ, DSZ);
            ln_kernel<<<Nc, 256, 0, stream>>>(xtc, xc, g2 + (size_t)l * DSZ, be2 + (size_t)l * DSZ);
        }
    }

    meanS_kernel<<<(BBATCH * DSZ) / 256, 256, 0, stream>>>(x, xm);
    fc_kernel<<<1, 128, 0, stream>>>(xm, fcW, fcb, fcA, fcBm, (float*)d_out);
}

// Round 7
// 2214.350 us; speedup vs baseline: 5.1989x; 1.0200x over previous
//
#include <hip/hip_runtime.h>
#include <hip/hip_bf16.h>

#define VSZ   32000
#define DSZ   768
#define HN    12
#define HIDSZ 3072
#define NL    2
#define CN    2
#define RR    8
#define SCALEF 2.0f
#define BBATCH 64
#define SSEQ  512
#define HDIM  64
#define NTOK  (BBATCH*SSEQ)   // 32768
#define QKVM  (3*DSZ)         // 2304 — stacked QKV output width

typedef __attribute__((ext_vector_type(8))) short bf16x8;   // 8 bf16 (4 VGPRs)
typedef __attribute__((ext_vector_type(4))) float floatx4;

__device__ __forceinline__ unsigned short f2bf_raw(float f) {
    __hip_bfloat16 h = __float2bfloat16(f);
    return __builtin_bit_cast(unsigned short, h);
}
__device__ __forceinline__ float bf2f(__hip_bfloat16 h) {
    return __bfloat162float(h);
}

// ---------------------------------------------------------------------------
__device__ __forceinline__ void gload16(const void* g, void* l) {
    __builtin_amdgcn_global_load_lds(
        (const __attribute__((address_space(1))) unsigned int*)g,
        (__attribute__((address_space(3))) unsigned int*)l, 16, 0, 0);
}

// ---------------------------------------------------------------------------
// Embedding -> bf16 x
// ---------------------------------------------------------------------------
__global__ __launch_bounds__(256) void embed_kernel(
    const int* __restrict__ tokens, const float* __restrict__ embW,
    const float* __restrict__ embA, const float* __restrict__ embB,
    __hip_bfloat16* __restrict__ xb)
{
    int n = blockIdx.x;            // n = s*B + b
    int s = n / BBATCH, b = n % BBATCH;
    int tok = tokens[b * SSEQ + s];
    __shared__ float a[RR];
    if (threadIdx.x < RR) a[threadIdx.x] = embA[(size_t)threadIdx.x * VSZ + tok];
    __syncthreads();
    for (int d = threadIdx.x; d < DSZ; d += 256) {
        float val = embW[(size_t)tok * DSZ + d];
        float lo = 0.f;
        #pragma unroll
        for (int r = 0; r < RR; ++r) lo += a[r] * embB[d * RR + r];
        xb[(size_t)n * DSZ + d] = __float2bfloat16(val + SCALEF * lo);
    }
}

// ---------------------------------------------------------------------------
// Effective weight (LoRA folded) -> bf16.  grid = (K/256, M)
// ---------------------------------------------------------------------------
__global__ __launch_bounds__(256) void weff_kernel(
    const float* __restrict__ W, const float* __restrict__ A,
    const float* __restrict__ Bm, __hip_bfloat16* __restrict__ Weff, int K)
{
    int i = blockIdx.x * 256 + threadIdx.x;
    int o = blockIdx.y;
    float acc = W[(size_t)o * K + i];
    #pragma unroll
    for (int r = 0; r < RR; ++r)
        acc += SCALEF * Bm[o * RR + r] * A[(size_t)r * K + i];
    Weff[(size_t)o * K + i] = __float2bfloat16(acc);
}

__global__ __launch_bounds__(256) void biascat_kernel(
    const float* __restrict__ b0, const float* __restrict__ b1v,
    const float* __restrict__ b2v, float* __restrict__ out)
{
    int t = blockIdx.y * 256 + threadIdx.x;   // 0..767
    const float* src = (blockIdx.x == 0) ? b0 : (blockIdx.x == 1) ? b1v : b2v;
    out[blockIdx.x * DSZ + t] = src[t];
}

// ---------------------------------------------------------------------------
// bf16 MFMA GEMM: Y[n,m] = bf16( X@W^T + bias (+ res) ), optional relu.
// 128x128 tile, BK=64 (XOR-swizzled LDS), 256 thr = 4 waves (2x2),
// each wave 4x4 MFMA 16x16x32 per 32-K sub-iteration (2 per staging round).
//
// LDS layout: slot s in [0,1024) holds 8 shorts at offset s*8.
// slot(row,k8) = row*8 + (k8 ^ (row&7)); staged via the global-fetch side
// (lane t of iter it fills slot it*256+t, so it FETCHES the element that
// belongs there). Permutation stays within one 128B line -> coalesced.
// ---------------------------------------------------------------------------
#define GT  128
#define GKK 64

template<bool RELU, bool ADDRES>
__global__ __launch_bounds__(256) void mgemm_kernel(
    const __hip_bfloat16* __restrict__ X, const __hip_bfloat16* __restrict__ W,
    const float* __restrict__ bias, const __hip_bfloat16* __restrict__ res,
    __hip_bfloat16* __restrict__ Y, int K, int ldx, int ldy)
{
    __shared__ unsigned short Xs[GT * GKK];   // 16 KB
    __shared__ unsigned short Ws[GT * GKK];   // 16 KB
    const int t    = threadIdx.x;
    const int n0   = blockIdx.x * GT;
    const int m0   = blockIdx.y * GT;
    const int wv   = t >> 6;
    const int lane = t & 63;
    const int wr   = (wv >> 1) * 64;   // wave row offset in tile
    const int wc   = (wv & 1) * 64;    // wave col offset in tile
    const int fm   = lane & 15;        // fragment free index
    const int fq   = lane >> 4;        // quad 0..3

    floatx4 acc[4][4];
    #pragma unroll
    for (int i = 0; i < 4; ++i)
        #pragma unroll
        for (int j = 0; j < 4; ++j)
            acc[i][j] = (floatx4){0.f, 0.f, 0.f, 0.f};

    const unsigned short* Xg = (const unsigned short*)X + (size_t)n0 * ldx;
    const unsigned short* Wg = (const unsigned short*)W + (size_t)m0 * K;

    // staging: slot = it*256 + t; row = slot>>3; fetched k8 = (t&7) ^ (row&7)
    const int srow = t >> 3;                          // row 0..31 per pass
    const int sk   = ((t & 7) ^ (srow & 7)) * 8;      // swizzled k offset (elems)

    // fragment read slots (c=0 sub-iter); c=1 is slot ^ 4  (shorts: ^32)
    int xsl[4], wsl[4];
    #pragma unroll
    for (int i = 0; i < 4; ++i) {
        xsl[i] = ((wr + i * 16 + fm) * 8 + (fq ^ (fm & 7))) * 8;
        wsl[i] = ((wc + i * 16 + fm) * 8 + (fq ^ (fm & 7))) * 8;
    }

    for (int k0 = 0; k0 < K; k0 += GKK) {
        __syncthreads();
        #pragma unroll
        for (int it = 0; it < 4; ++it) {
            int row = it * 32 + srow;
            int seg = (it * 256 + t) * 8;
            gload16(Xg + (size_t)row * ldx + k0 + sk, &Xs[seg]);
            gload16(Wg + (size_t)row * K   + k0 + sk, &Ws[seg]);
        }
        __syncthreads();

        #pragma unroll
        for (int c = 0; c < 2; ++c) {
            const int cx = c * 32;   // shorts offset XOR for slot^4
            bf16x8 af[4], bfr[4];
            #pragma unroll
            for (int i = 0; i < 4; ++i) {
                af[i]  = *(const bf16x8*)&Xs[xsl[i] ^ cx];
                bfr[i] = *(const bf16x8*)&Ws[wsl[i] ^ cx];
            }
            #pragma unroll
            for (int i = 0; i < 4; ++i)
                #pragma unroll
                for (int j = 0; j < 4; ++j)
                    acc[i][j] = __builtin_amdgcn_mfma_f32_16x16x32_bf16(
                        af[i], bfr[j], acc[i][j], 0, 0, 0);
        }
    }

    // epilogue: D row (token) = wr + i*16 + fq*4 + r ; D col (feat) = wc + j*16 + fm
    #pragma unroll
    for (int j = 0; j < 4; ++j) {
        int col = m0 + wc + j * 16 + fm;
        float bj = bias[col];
        #pragma unroll
        for (int i = 0; i < 4; ++i) {
            int row = n0 + wr + i * 16 + fq * 4;
            #pragma unroll
            for (int r = 0; r < 4; ++r) {
                float v = acc[i][j][r] + bj;
                if (RELU) v = fmaxf(v, 0.f);
                size_t off = (size_t)(row + r) * ldy + col;
                if (ADDRES) v += bf2f(res[off]);
                Y[off] = __float2bfloat16(v);
            }
        }
    }
}

// ---------------------------------------------------------------------------
// MFMA attention over the BATCH axis. qkvb bf16 rows stride QKVM: [Q|K|V].
// Block = one (s',h), 4 waves; wave w owns score rows 16w..16w+15.
// Output bf16 -> aob (stride DSZ). grid = schunk*HN.
// ---------------------------------------------------------------------------
__global__ __launch_bounds__(256) void attn_kernel(
    const __hip_bfloat16* __restrict__ qkvb, __hip_bfloat16* __restrict__ aob)
{
    __shared__ __align__(16) unsigned short Vt[64][72];      // Vt[d][c] = V[c][d]
    __shared__ __align__(16) unsigned short Ps[4][16][72];   // per-wave P rows
    const int t    = threadIdx.x;
    const int wv   = t >> 6;
    const int lane = t & 63;
    const int fm   = lane & 15;
    const int fq   = lane >> 4;
    const int sp   = blockIdx.x / HN;
    const int h    = blockIdx.x % HN;
    const unsigned short* qg =
        (const unsigned short*)qkvb + (size_t)sp * BBATCH * QKVM + h * HDIM;

    // ---- stage V transposed: thread (c=lane, d0=wv*16) reads V[c][d0..d0+15]
    {
        const int c = lane, d0 = wv * 16;
        const unsigned short* vrow = qg + 2 * DSZ + (size_t)c * QKVM + d0;
        bf16x8 v0 = *(const bf16x8*)vrow;
        bf16x8 v1 = *(const bf16x8*)(vrow + 8);
        #pragma unroll
        for (int i = 0; i < 8; ++i) {
            Vt[d0 + i][c]     = (unsigned short)v0[i];
            Vt[d0 + 8 + i][c] = (unsigned short)v1[i];
        }
    }

    // ---- Q A-frags (own 16 rows) and K B-frags (all 64 cols), direct global
    const unsigned short* qrow = qg + (size_t)(wv * 16 + fm) * QKVM + fq * 8;
    bf16x8 af0 = *(const bf16x8*)qrow;
    bf16x8 af1 = *(const bf16x8*)(qrow + 32);
    bf16x8 bk0[4], bk1[4];
    #pragma unroll
    for (int jt = 0; jt < 4; ++jt) {
        const unsigned short* krow = qg + DSZ + (size_t)(jt * 16 + fm) * QKVM + fq * 8;
        bk0[jt] = *(const bf16x8*)krow;
        bk1[jt] = *(const bf16x8*)(krow + 32);
    }

    // ---- scores: 16x64 per wave, fp32 acc
    floatx4 sc[4];
    #pragma unroll
    for (int jt = 0; jt < 4; ++jt) sc[jt] = (floatx4){0.f, 0.f, 0.f, 0.f};
    #pragma unroll
    for (int jt = 0; jt < 4; ++jt) {
        sc[jt] = __builtin_amdgcn_mfma_f32_16x16x32_bf16(af0, bk0[jt], sc[jt], 0, 0, 0);
        sc[jt] = __builtin_amdgcn_mfma_f32_16x16x32_bf16(af1, bk1[jt], sc[jt], 0, 0, 0);
    }
    #pragma unroll
    for (int jt = 0; jt < 4; ++jt)
        #pragma unroll
        for (int r = 0; r < 4; ++r) sc[jt][r] *= 0.125f;

    // ---- softmax per row (row = fq*4+r, spread over 16 lanes x 4 jt)
    float pr[4][4];
    #pragma unroll
    for (int r = 0; r < 4; ++r) {
        float m = fmaxf(fmaxf(sc[0][r], sc[1][r]), fmaxf(sc[2][r], sc[3][r]));
        #pragma unroll
        for (int msk = 1; msk < 16; msk <<= 1) m = fmaxf(m, __shfl_xor(m, msk, 64));
        float s = 0.f;
        #pragma unroll
        for (int jt = 0; jt < 4; ++jt) { pr[jt][r] = __expf(sc[jt][r] - m); s += pr[jt][r]; }
        #pragma unroll
        for (int msk = 1; msk < 16; msk <<= 1) s += __shfl_xor(s, msk, 64);
        float inv = 1.f / s;
        #pragma unroll
        for (int jt = 0; jt < 4; ++jt) pr[jt][r] *= inv;
    }

    // ---- P -> LDS (C-layout -> A-layout round trip), bf16
    #pragma unroll
    for (int jt = 0; jt < 4; ++jt)
        #pragma unroll
        for (int r = 0; r < 4; ++r)
            Ps[wv][fq * 4 + r][jt * 16 + fm] = f2bf_raw(pr[jt][r]);

    __syncthreads();   // Vt (cross-wave) ready; Ps is wave-local

    // ---- PV: A = P (own rows), B = Vt
    bf16x8 ap0 = *(const bf16x8*)&Ps[wv][fm][fq * 8];
    bf16x8 ap1 = *(const bf16x8*)&Ps[wv][fm][32 + fq * 8];
    floatx4 ov[4];
    #pragma unroll
    for (int jt = 0; jt < 4; ++jt) ov[jt] = (floatx4){0.f, 0.f, 0.f, 0.f};
    #pragma unroll
    for (int jt = 0; jt < 4; ++jt) {
        bf16x8 bv0 = *(const bf16x8*)&Vt[jt * 16 + fm][fq * 8];
        bf16x8 bv1 = *(const bf16x8*)&Vt[jt * 16 + fm][32 + fq * 8];
        ov[jt] = __builtin_amdgcn_mfma_f32_16x16x32_bf16(ap0, bv0, ov[jt], 0, 0, 0);
        ov[jt] = __builtin_amdgcn_mfma_f32_16x16x32_bf16(ap1, bv1, ov[jt], 0, 0, 0);
    }

    // ---- write O bf16: row b = 16wv + 4fq + r, col d = jt*16+fm
    __hip_bfloat16* obase = aob + ((size_t)sp * BBATCH + wv * 16 + fq * 4) * DSZ + h * HDIM;
    #pragma unroll
    for (int jt = 0; jt < 4; ++jt)
        #pragma unroll
        for (int r = 0; r < 4; ++r)
            obase[(size_t)r * DSZ + jt * 16 + fm] = __float2bfloat16(ov[jt][r]);
}

// ---------------------------------------------------------------------------
// LayerNorm: src bf16 -> dst bf16 (separate buffers), fp32 stats.
// ---------------------------------------------------------------------------
__device__ __forceinline__ float block_sum256(float vsum, volatile float* red) {
    #pragma unroll
    for (int off = 32; off > 0; off >>= 1) vsum += __shfl_down(vsum, off, 64);
    if ((threadIdx.x & 63) == 0) red[threadIdx.x >> 6] = vsum;
    __syncthreads();
    return red[0] + red[1] + red[2] + red[3];
}

__global__ __launch_bounds__(256) void ln_kernel(
    const __hip_bfloat16* __restrict__ src, __hip_bfloat16* __restrict__ dst,
    const float* __restrict__ g, const float* __restrict__ be)
{
    __shared__ float red1[4];
    __shared__ float red2[4];
    const int n = blockIdx.x;
    const int t = threadIdx.x;
    const __hip_bfloat16* row = src + (size_t)n * DSZ;
    __hip_bfloat16* orow = dst + (size_t)n * DSZ;
    float v0 = bf2f(row[t]), v1 = bf2f(row[t + 256]), v2 = bf2f(row[t + 512]);
    float total = block_sum256(v0 + v1 + v2, red1);
    float mean = total * (1.0f / DSZ);
    float d0 = v0 - mean, d1 = v1 - mean, d2 = v2 - mean;
    __syncthreads();
    float var = block_sum256(d0 * d0 + d1 * d1 + d2 * d2, red2) * (1.0f / DSZ);
    float rstd = rsqrtf(var + 1e-5f);
    orow[t]       = __float2bfloat16(d0 * rstd * g[t]       + be[t]);
    orow[t + 256] = __float2bfloat16(d1 * rstd * g[t + 256] + be[t + 256]);
    orow[t + 512] = __float2bfloat16(d2 * rstd * g[t + 512] + be[t + 512]);
}

// ---------------------------------------------------------------------------
__global__ __launch_bounds__(256) void meanS_kernel(
    const __hip_bfloat16* __restrict__ x, float* __restrict__ xm)
{
    int idx = blockIdx.x * 256 + threadIdx.x;   // over B*D, d fastest
    int b = idx / DSZ, d = idx % DSZ;
    float acc = 0.f;
    for (int s = 0; s < SSEQ; ++s)
        acc += bf2f(x[((size_t)s * BBATCH + b) * DSZ + d]);
    xm[idx] = acc * (1.0f / SSEQ);
}

__global__ __launch_bounds__(128) void fc_kernel(
    const float* __restrict__ xm, const float* __restrict__ fcW,
    const float* __restrict__ fcb, const float* __restrict__ fcA,
    const float* __restrict__ fcBm, float* __restrict__ out)
{
    int t = threadIdx.x;
    if (t >= BBATCH * CN) return;
    int b = t / CN, c = t % CN;
    float acc = fcb[c];
    float lora[RR];
    #pragma unroll
    for (int r = 0; r < RR; ++r) lora[r] = 0.f;
    for (int d = 0; d < DSZ; ++d) {
        float xv = xm[b * DSZ + d];
        acc += xv * fcW[c * DSZ + d];
        #pragma unroll
        for (int r = 0; r < RR; ++r) lora[r] += xv * fcA[r * DSZ + d];
    }
    float lo = 0.f;
    #pragma unroll
    for (int r = 0; r < RR; ++r) lo += lora[r] * fcBm[c * RR + r];
    out[b * CN + c] = acc + SCALEF * lo;
}

// ---------------------------------------------------------------------------
extern "C" void kernel_launch(void* const* d_in, const int* in_sizes, int n_in,
                              void* d_out, int out_size, void* d_ws, size_t ws_size,
                              hipStream_t stream) {
    const int*   tokens = (const int*)  d_in[0];
    const float* embW   = (const float*)d_in[1];
    const float* embA   = (const float*)d_in[2];
    const float* embB   = (const float*)d_in[3];
    const float* Wq = (const float*)d_in[4],  *bq = (const float*)d_in[5],
               * Aq = (const float*)d_in[6],  *Bq = (const float*)d_in[7];
    const float* Wk = (const float*)d_in[8],  *bk = (const float*)d_in[9],
               * Ak = (const float*)d_in[10], *Bk = (const float*)d_in[11];
    const float* Wv = (const float*)d_in[12], *bv = (const float*)d_in[13],
               * Av = (const float*)d_in[14], *Bv = (const float*)d_in[15];
    const float* Wo = (const float*)d_in[16], *bo = (const float*)d_in[17],
               * Ao = (const float*)d_in[18], *Bo = (const float*)d_in[19];
    const float* W1 = (const float*)d_in[20], *b1 = (const float*)d_in[21],
               * A1 = (const float*)d_in[22], *B1 = (const float*)d_in[23];
    const float* W2 = (const float*)d_in[24], *b2 = (const float*)d_in[25],
               * A2 = (const float*)d_in[26], *B2 = (const float*)d_in[27];
    const float* g1 = (const float*)d_in[28], *be1 = (const float*)d_in[29];
    const float* g2 = (const float*)d_in[30], *be2 = (const float*)d_in[31];
    const float* fcW = (const float*)d_in[32], *fcb = (const float*)d_in[33];
    const float* fcA = (const float*)d_in[34], *fcBm = (const float*)d_in[35];

    const size_t ND = (size_t)NTOK * DSZ;

    // ---- workspace layout (float units; all sections multiple of 4) ------
    const size_t X_F    = ND / 2;                       // bf16 x (LN out / residual base)
    const size_t XT_F   = ND / 2;                       // bf16 xt (pre-LN sum)
    const size_t WQKV_F = (size_t)QKVM * DSZ / 2;
    const size_t WO_F   = (size_t)DSZ * DSZ / 2;
    const size_t WF1_F  = (size_t)HIDSZ * DSZ / 2;
    const size_t WF2_F  = (size_t)DSZ * HIDSZ / 2;
    const size_t BQKV_F = 2304;
    const size_t XM_F   = (size_t)BBATCH * DSZ;
    const size_t fixedF = X_F + XT_F + WQKV_F + WO_F + WF1_F + WF2_F + BQKV_F + XM_F;
    const size_t availF = ws_size / 4;

    int schunk = 2;
    const int cand[6] = {512, 256, 128, 64, 32, 16};
    for (int i = 0; i < 6; ++i) {
        // per-chunk: bf16 qkv (Nc*2304) + bf16 aob (Nc*768) == bf16 h (Nc*3072)
        size_t chunkF = (size_t)cand[i] * BBATCH * (HIDSZ / 2);
        if (fixedF + chunkF <= availF) { schunk = cand[i]; break; }
    }
    const int Nc = schunk * BBATCH;
    const int nchunk = SSEQ / schunk;

    float* p = (float*)d_ws;
    __hip_bfloat16* x  = (__hip_bfloat16*)p;     p += X_F;
    __hip_bfloat16* xt = (__hip_bfloat16*)p;     p += XT_F;
    __hip_bfloat16* wqkvb = (__hip_bfloat16*)p;  p += WQKV_F;
    __hip_bfloat16* wob   = (__hip_bfloat16*)p;  p += WO_F;
    __hip_bfloat16* wf1b  = (__hip_bfloat16*)p;  p += WF1_F;
    __hip_bfloat16* wf2b  = (__hip_bfloat16*)p;  p += WF2_F;
    float* bqkv = p;                             p += BQKV_F;
    float* xm   = p;                             p += XM_F;
    __hip_bfloat16* cb16 = (__hip_bfloat16*)p;   // chunk: qkvb|aob, later h
    __hip_bfloat16* qkvb = cb16;
    __hip_bfloat16* aob  = cb16 + (size_t)Nc * QKVM;
    __hip_bfloat16* hb   = cb16;

    embed_kernel<<<NTOK, 256, 0, stream>>>(tokens, embW, embA, embB, x);

    for (int l = 0; l < NL; ++l) {
        const size_t oDD = (size_t)l * DSZ * DSZ;
        const size_t oDH = (size_t)l * HIDSZ * DSZ;
        const size_t oRD = (size_t)l * RR * DSZ;
        const size_t oRH = (size_t)l * RR * HIDSZ;
        const size_t oDR = (size_t)l * DSZ * RR;
        const size_t oHR = (size_t)l * HIDSZ * RR;

        weff_kernel<<<dim3(3, DSZ), 256, 0, stream>>>(Wq + oDD, Aq + oRD, Bq + oDR, wqkvb, DSZ);
        weff_kernel<<<dim3(3, DSZ), 256, 0, stream>>>(Wk + oDD, Ak + oRD, Bk + oDR, wqkvb + (size_t)DSZ * DSZ, DSZ);
        weff_kernel<<<dim3(3, DSZ), 256, 0, stream>>>(Wv + oDD, Av + oRD, Bv + oDR, wqkvb + (size_t)2 * DSZ * DSZ, DSZ);
        biascat_kernel<<<dim3(3, 3), 256, 0, stream>>>(bq + (size_t)l * DSZ, bk + (size_t)l * DSZ, bv + (size_t)l * DSZ, bqkv);
        weff_kernel<<<dim3(3, DSZ), 256, 0, stream>>>(Wo + oDD, Ao + oRD, Bo + oDR, wob, DSZ);
        weff_kernel<<<dim3(3, HIDSZ), 256, 0, stream>>>(W1 + oDH, A1 + oRD, B1 + oHR, wf1b, DSZ);
        weff_kernel<<<dim3(12, DSZ), 256, 0, stream>>>(W2 + oDH, A2 + oRH, B2 + oDR, wf2b, HIDSZ);

        const float* bo_l = bo + (size_t)l * DSZ;
        const float* b1_l = b1 + (size_t)l * HIDSZ;
        const float* b2_l = b2 + (size_t)l * DSZ;

        for (int c = 0; c < nchunk; ++c) {
            __hip_bfloat16* xc  = x  + (size_t)c * Nc * DSZ;
            __hip_bfloat16* xtc = xt + (size_t)c * Nc * DSZ;

            // QKV stacked: (Nc x 768) @ (2304 x 768)^T -> bf16 qkvb
            mgemm_kernel<false, false><<<dim3(Nc / GT, QKVM / GT), 256, 0, stream>>>(
                xc, wqkvb, bqkv, nullptr, qkvb, DSZ, DSZ, QKVM);

            attn_kernel<<<schunk * HN, 256, 0, stream>>>(qkvb, aob);

            // O-proj + residual(x) -> xt, then LN1: xt -> x
            mgemm_kernel<false, true><<<dim3(Nc / GT, DSZ / GT), 256, 0, stream>>>(
                aob, wob, bo_l, xc, xtc, DSZ, DSZ, DSZ);
            ln_kernel<<<Nc, 256, 0, stream>>>(xtc, xc, g1 + (size_t)l * DSZ, be1 + (size_t)l * DSZ);

            // FF1 (relu) -> bf16 h (qkv/aob dead, reuse chunk buffer)
            mgemm_kernel<true, false><<<dim3(Nc / GT, HIDSZ / GT), 256, 0, stream>>>(
                xc, wf1b, b1_l, nullptr, hb, DSZ, DSZ, HIDSZ);

            // FF2 + residual(x) -> xt, then LN2: xt -> x
            mgemm_kernel<false, true><<<dim3(Nc / GT, DSZ / GT), 256, 0, stream>>>(
                hb, wf2b, b2_l, xc, xtc, HIDSZ, HIDSZ, DSZ);
            ln_kernel<<<Nc, 256, 0, stream>>>(xtc, xc, g2 + (size_t)l * DSZ, be2 + (size_t)l * DSZ);
        }
    }

    meanS_kernel<<<(BBATCH * DSZ) / 256, 256, 0, stream>>>(x, xm);
    fc_kernel<<<1, 128, 0, stream>>>(xm, fcW, fcb, fcA, fcBm, (float*)d_out);
}